// Round 8
// baseline (2005.868 us; speedup 1.0000x reference)
//
#include <hip/hip_runtime.h>
#include <math.h>

// Problem constants (from reference)
#define N0   50000
#define E0   800000
#define HD   128          // D == H == 128
#define EHD  16
#define KP1  25000
#define KP2  12500
#define KP3  6250
#define BN_SCALE 0.9999950000374997f   // 1/sqrt(1+1e-5)
#define NEG_SLOPE 0.01f
// compacted-edge capacity per level (expected E/4^i, wide margin; inputs are fixed seed)
#define E1C  400000
#define E2C  120000
#define E3C  40000
#define NBE  782          // ceil(E0/1024)
#define CSB  782          // colsum phase-1 blocks
#define SELB 128          // pool-select grid

// ---------- helpers ----------
__device__ __forceinline__ unsigned fenc(float f) {
    unsigned u = __float_as_uint(f);
    return (u & 0x80000000u) ? ~u : (u | 0x80000000u);
}

// generation-based grid barrier; all blocks of the grid must be co-resident.
__device__ __forceinline__ void grid_barrier(unsigned* bar, unsigned nb) {
    __syncthreads();
    if (threadIdx.x == 0) {
        unsigned gen = __hip_atomic_load(&bar[1], __ATOMIC_RELAXED, __HIP_MEMORY_SCOPE_AGENT);
        unsigned prev = __hip_atomic_fetch_add(&bar[0], 1u, __ATOMIC_ACQ_REL, __HIP_MEMORY_SCOPE_AGENT);
        if (prev == nb - 1u) {
            __hip_atomic_store(&bar[0], 0u, __ATOMIC_RELAXED, __HIP_MEMORY_SCOPE_AGENT);
            __hip_atomic_fetch_add(&bar[1], 1u, __ATOMIC_ACQ_REL, __HIP_MEMORY_SCOPE_AGENT);
        } else {
            while (__hip_atomic_load(&bar[1], __ATOMIC_ACQUIRE, __HIP_MEMORY_SCOPE_AGENT) == gen) {
                __builtin_amdgcn_s_sleep(2);
            }
        }
    }
    __syncthreads();
}

// ---------- edge embedding: per-block partial min/max ----------
__global__ void k_edge_ew(const float* __restrict__ ea, const float* __restrict__ Ww,
                          const float* __restrict__ Wb, float* __restrict__ ew,
                          float2* __restrict__ partials, int E) {
    int e = blockIdx.x * 256 + threadIdx.x;
    float mn = 3.4e38f, mx = -3.4e38f;
    if (e < E) {
        const float4* a4 = (const float4*)(ea + (size_t)e * EHD);
        float s = Wb[0];
        #pragma unroll
        for (int q = 0; q < 4; ++q) {
            float4 a = a4[q];
            s += a.x * Ww[q*4+0] + a.y * Ww[q*4+1] + a.z * Ww[q*4+2] + a.w * Ww[q*4+3];
        }
        ew[e] = s;
        mn = s; mx = s;
    }
    #pragma unroll
    for (int off = 32; off > 0; off >>= 1) {
        mn = fminf(mn, __shfl_xor(mn, off));
        mx = fmaxf(mx, __shfl_xor(mx, off));
    }
    __shared__ float smn[4], smx[4];
    int lane = threadIdx.x & 63, wid = threadIdx.x >> 6;
    if (lane == 0) { smn[wid] = mn; smx[wid] = mx; }
    __syncthreads();
    if (threadIdx.x == 0) {
        float a = fminf(fminf(smn[0], smn[1]), fminf(smn[2], smn[3]));
        float b = fmaxf(fmaxf(smx[0], smx[1]), fmaxf(smx[2], smx[3]));
        partials[blockIdx.x] = make_float2(a, b);
    }
}

__global__ void __launch_bounds__(1024)
k_reduce_mm(const float2* __restrict__ partials, int nb, float* __restrict__ mmv) {
    float mn = 3.4e38f, mx = -3.4e38f;
    for (int i = threadIdx.x; i < nb; i += 1024) {
        float2 t = partials[i];
        mn = fminf(mn, t.x); mx = fmaxf(mx, t.y);
    }
    #pragma unroll
    for (int off = 32; off > 0; off >>= 1) {
        mn = fminf(mn, __shfl_xor(mn, off));
        mx = fmaxf(mx, __shfl_xor(mx, off));
    }
    __shared__ float smn[16], smx[16];
    int lane = threadIdx.x & 63, wid = threadIdx.x >> 6;
    if (lane == 0) { smn[wid] = mn; smx[wid] = mx; }
    __syncthreads();
    if (threadIdx.x == 0) {
        for (int w = 1; w < 16; ++w) { mn = fminf(mn, smn[w]); mx = fmaxf(mx, smx[w]); }
        mmv[0] = mn; mmv[1] = mx;
    }
}

// normalize + fused level-0 CSR degree count (cnt must be zeroed)
__global__ void k_ew_norm_count(float* __restrict__ ew, const float* __restrict__ mmv,
                                const int* __restrict__ dst, int* __restrict__ cnt, int E) {
    int e = blockIdx.x * 256 + threadIdx.x;
    if (e >= E) return;
    float mn = mmv[0];
    float sc = 1.0f / ((mmv[1] - mn) + 1e-7f);
    float w = (ew[e] - mn) * sc;
    ew[e] = w;
    if (w != 0.0f) atomicAdd(&cnt[dst[e]], 1);
}

// ---------- n x 128 @ 128 x 128 GEMM, fused optional BN / unpool-scatter on A ----------
#define GT_ROWS 64
__global__ void __launch_bounds__(256)
k_gemm128(const float* __restrict__ A, const float* __restrict__ W,
          float* __restrict__ C, int n,
          const float* __restrict__ gs, const float* __restrict__ gb,
          const float* __restrict__ up_h, const int* __restrict__ up_pos) {
    __shared__ float As[GT_ROWS][132];   // +4 pad
    int tid = threadIdx.x;               // 256
    int row0 = blockIdx.x * GT_ROWS;
    int maxr = n - row0;
    {
        #pragma unroll
        for (int it = 0; it < 8; ++it) {
            int idx = it * 256 + tid;
            int r = idx >> 5, q = idx & 31;
            float4 v = make_float4(0.f, 0.f, 0.f, 0.f);
            if (r < maxr) {
                v = ((const float4*)(A + (size_t)(row0 + r) * HD))[q];
                if (up_pos) {
                    int sl = up_pos[row0 + r];
                    if (sl >= 0) {
                        float4 u = ((const float4*)(up_h + (size_t)sl * HD))[q];
                        v.x += u.x; v.y += u.y; v.z += u.z; v.w += u.w;
                    }
                }
                if (gs) {
                    float4 g4 = ((const float4*)gs)[q];
                    float4 b4 = ((const float4*)gb)[q];
                    v.x = v.x * (g4.x * BN_SCALE) + b4.x;
                    v.y = v.y * (g4.y * BN_SCALE) + b4.y;
                    v.z = v.z * (g4.z * BN_SCALE) + b4.z;
                    v.w = v.w * (g4.w * BN_SCALE) + b4.w;
                }
            }
            *(float4*)&As[r][q * 4] = v;
        }
    }
    __syncthreads();
    int cg = tid & 31;
    int rg = tid >> 5;
    float4 acc[8];
    #pragma unroll
    for (int j = 0; j < 8; ++j) acc[j] = make_float4(0.f, 0.f, 0.f, 0.f);
    const float4* W4 = (const float4*)W;
    #pragma unroll 4
    for (int k = 0; k < HD; k += 4) {
        float4 w0 = W4[(k + 0) * 32 + cg];
        float4 w1 = W4[(k + 1) * 32 + cg];
        float4 w2 = W4[(k + 2) * 32 + cg];
        float4 w3 = W4[(k + 3) * 32 + cg];
        #pragma unroll
        for (int jj = 0; jj < 4; ++jj) {
            float4 a = *(const float4*)&As[4 * rg + jj][k];
            acc[jj].x += a.x * w0.x + a.y * w1.x + a.z * w2.x + a.w * w3.x;
            acc[jj].y += a.x * w0.y + a.y * w1.y + a.z * w2.y + a.w * w3.y;
            acc[jj].z += a.x * w0.z + a.y * w1.z + a.z * w2.z + a.w * w3.z;
            acc[jj].w += a.x * w0.w + a.y * w1.w + a.z * w2.w + a.w * w3.w;
        }
        #pragma unroll
        for (int jj = 0; jj < 4; ++jj) {
            float4 a = *(const float4*)&As[32 + 4 * rg + jj][k];
            acc[4 + jj].x += a.x * w0.x + a.y * w1.x + a.z * w2.x + a.w * w3.x;
            acc[4 + jj].y += a.x * w0.y + a.y * w1.y + a.z * w2.y + a.w * w3.y;
            acc[4 + jj].z += a.x * w0.z + a.y * w1.z + a.z * w2.z + a.w * w3.z;
            acc[4 + jj].w += a.x * w0.w + a.y * w1.w + a.z * w2.w + a.w * w3.w;
        }
    }
    #pragma unroll
    for (int jj = 0; jj < 4; ++jj) {
        int r = 4 * rg + jj;
        if (r < maxr) *(float4*)&C[(size_t)(row0 + r) * HD + 4 * cg] = acc[jj];
    }
    #pragma unroll
    for (int jj = 0; jj < 4; ++jj) {
        int r = 32 + 4 * rg + jj;
        if (r < maxr) *(float4*)&C[(size_t)(row0 + r) * HD + 4 * cg] = acc[4 + jj];
    }
}

// ---------- CSR build: fused chunk-sum + block-scan (done-counter) ----------
__global__ void k_sum_scan(const int* __restrict__ cnt, int* __restrict__ bsum, int n,
                           int* __restrict__ totalOut, unsigned* __restrict__ dctr) {
    int base = blockIdx.x * 1024;
    int s = 0;
    #pragma unroll
    for (int it = 0; it < 4; ++it) {
        int i = base + it * 256 + threadIdx.x;
        if (i < n) s += cnt[i];
    }
    __shared__ int ws[4];
    __shared__ int lastFlag;
    int lane = threadIdx.x & 63, wid = threadIdx.x >> 6;
    #pragma unroll
    for (int off = 32; off > 0; off >>= 1) s += __shfl_down(s, off);
    if (lane == 0) ws[wid] = s;
    __syncthreads();
    if (threadIdx.x == 0) {
        __hip_atomic_store(&bsum[blockIdx.x], ws[0] + ws[1] + ws[2] + ws[3],
                           __ATOMIC_RELAXED, __HIP_MEMORY_SCOPE_AGENT);
        unsigned prev = __hip_atomic_fetch_add(dctr, 1u, __ATOMIC_ACQ_REL, __HIP_MEMORY_SCOPE_AGENT);
        lastFlag = (prev == gridDim.x - 1);
    }
    __syncthreads();
    if (!lastFlag) return;
    if (threadIdx.x < 64) {
        int nb = gridDim.x;
        int t = threadIdx.x;
        int v = (t < nb) ? __hip_atomic_load(&bsum[t], __ATOMIC_RELAXED, __HIP_MEMORY_SCOPE_AGENT) : 0;
        int x = v;
        #pragma unroll
        for (int off = 1; off < 64; off <<= 1) {
            int y = __shfl_up(x, off);
            if (t >= off) x += y;
        }
        if (t < nb) bsum[t] = x - v;
        if (t == nb - 1) totalOut[0] = x;
    }
    if (threadIdx.x == 0)
        __hip_atomic_store(dctr, 0u, __ATOMIC_RELAXED, __HIP_MEMORY_SCOPE_AGENT);
}

__global__ void k_chunk_scan(const int* __restrict__ cnt, const int* __restrict__ bo,
                             int* __restrict__ rowptr, int* __restrict__ cursor, int n) {
    __shared__ int wsum[4];
    __shared__ int running;
    int base = blockIdx.x * 1024;
    if (threadIdx.x == 0) running = bo[blockIdx.x];
    __syncthreads();
    int lane = threadIdx.x & 63, wid = threadIdx.x >> 6;
    #pragma unroll
    for (int it = 0; it < 4; ++it) {
        int i = base + it * 256 + threadIdx.x;
        int v = (i < n) ? cnt[i] : 0;
        int x = v;
        #pragma unroll
        for (int off = 1; off < 64; off <<= 1) {
            int y = __shfl_up(x, off);
            if (lane >= off) x += y;
        }
        if (lane == 63) wsum[wid] = x;
        __syncthreads();
        int wb = 0;
        for (int w = 0; w < wid; ++w) wb += wsum[w];
        int excl = running + wb + x - v;
        if (i < n) { rowptr[i] = excl; cursor[i] = excl; }
        __syncthreads();
        if (threadIdx.x == 0) running += wsum[0] + wsum[1] + wsum[2] + wsum[3];
        __syncthreads();
    }
}

// packed CSR entry: {src, float_bits(w)} — one 8B store per edge (halves write-amp)
__global__ void k_csr_fill(const int* __restrict__ src, const int* __restrict__ dst,
                           const float* __restrict__ w, int* __restrict__ cursor,
                           int2* __restrict__ csr,
                           const int* __restrict__ EinPtr, int EinImm) {
    int Ein = EinPtr ? EinPtr[0] : EinImm;
    int e = blockIdx.x * 256 + threadIdx.x;
    if (e >= Ein) return;
    float wv = w[e];
    if (wv == 0.0f) return;
    int slot = atomicAdd(&cursor[dst[e]], 1);
    csr[slot] = make_int2(src[e], __float_as_int(wv));
}

// ---------- degree from CSR ----------
__global__ void k_deg_dinv(const int* __restrict__ rowptr, const int2* __restrict__ csr,
                           float fill, float* __restrict__ deg, float* __restrict__ dinv, int n) {
    int v = blockIdx.x * 256 + threadIdx.x;
    if (v >= n) return;
    float s = fill;
    int rs = rowptr[v], re = rowptr[v + 1];
    for (int j = rs; j < re; ++j) s += __int_as_float(csr[j].y);
    deg[v] = s;
    dinv[v] = rsqrtf(s);
}

// ---------- fused GCN gather: 2 neighbors/wave, float4/lane, 4x unroll ----------
__global__ void __launch_bounds__(256)
k_gcn_gather(const int* __restrict__ rowptr, const int2* __restrict__ csr,
             const float* __restrict__ deg, const float* __restrict__ dinv,
             const float* __restrict__ hW, const float* __restrict__ bias,
             float fill, int n, int lrelu, float* __restrict__ out) {
    int v = blockIdx.x * 4 + (threadIdx.x >> 6);
    int lane = threadIdx.x & 63;
    if (v >= n) return;
    int rs = rowptr[v], re = rowptr[v + 1];
    float dv = dinv[v];
    int half = lane >> 5;
    int qi = lane & 31;
    float4 acc = make_float4(0.f, 0.f, 0.f, 0.f);
    for (int base = rs; base < re; base += 64) {
        int idx = base + lane;
        int s_r = 0; float c_r = 0.f;
        if (idx < re) {
            int2 ent = csr[idx];
            s_r = ent.x;
            c_r = dinv[s_r] * __int_as_float(ent.y) * dv;
        }
        int cnt = min(64, re - base);
        int pairs = cnt >> 1;
        int t = 0;
        for (; t + 3 < pairs; t += 4) {
            int j0 = 2 * t + half, j1 = j0 + 2, j2 = j0 + 4, j3 = j0 + 6;
            int   s0 = __shfl(s_r, j0); float c0 = __shfl(c_r, j0);
            int   s1 = __shfl(s_r, j1); float c1 = __shfl(c_r, j1);
            int   s2 = __shfl(s_r, j2); float c2 = __shfl(c_r, j2);
            int   s3 = __shfl(s_r, j3); float c3 = __shfl(c_r, j3);
            float4 h0 = ((const float4*)(hW + (size_t)s0 * HD))[qi];
            float4 h1 = ((const float4*)(hW + (size_t)s1 * HD))[qi];
            float4 h2 = ((const float4*)(hW + (size_t)s2 * HD))[qi];
            float4 h3 = ((const float4*)(hW + (size_t)s3 * HD))[qi];
            acc.x += c0 * h0.x; acc.y += c0 * h0.y; acc.z += c0 * h0.z; acc.w += c0 * h0.w;
            acc.x += c1 * h1.x; acc.y += c1 * h1.y; acc.z += c1 * h1.z; acc.w += c1 * h1.w;
            acc.x += c2 * h2.x; acc.y += c2 * h2.y; acc.z += c2 * h2.z; acc.w += c2 * h2.w;
            acc.x += c3 * h3.x; acc.y += c3 * h3.y; acc.z += c3 * h3.z; acc.w += c3 * h3.w;
        }
        for (; t < pairs; ++t) {
            int j = 2 * t + half;
            int s = __shfl(s_r, j); float c = __shfl(c_r, j);
            float4 h0 = ((const float4*)(hW + (size_t)s * HD))[qi];
            acc.x += c * h0.x; acc.y += c * h0.y; acc.z += c * h0.z; acc.w += c * h0.w;
        }
        if (cnt & 1) {
            int j = cnt - 1;
            int s = __shfl(s_r, j); float c = __shfl(c_r, j);
            if (half == 0) {
                float4 h0 = ((const float4*)(hW + (size_t)s * HD))[qi];
                acc.x += c * h0.x; acc.y += c * h0.y; acc.z += c * h0.z; acc.w += c * h0.w;
            }
        }
    }
    acc.x += __shfl_xor(acc.x, 32);
    acc.y += __shfl_xor(acc.y, 32);
    acc.z += __shfl_xor(acc.z, 32);
    acc.w += __shfl_xor(acc.w, 32);
    if (half == 0) {
        float4 hs = ((const float4*)(hW + (size_t)v * HD))[qi];
        float sc = fill / deg[v];
        float4 b4 = ((const float4*)bias)[qi];
        float4 o;
        o.x = acc.x + sc * hs.x + b4.x;
        o.y = acc.y + sc * hs.y + b4.y;
        o.z = acc.z + sc * hs.z + b4.z;
        o.w = acc.w + sc * hs.w + b4.w;
        if (lrelu) {
            o.x = o.x > 0.f ? o.x : NEG_SLOPE * o.x;
            o.y = o.y > 0.f ? o.y : NEG_SLOPE * o.y;
            o.z = o.z > 0.f ? o.z : NEG_SLOPE * o.z;
            o.w = o.w > 0.f ? o.w : NEG_SLOPE * o.w;
        }
        ((float4*)(out + (size_t)v * HD))[qi] = o;
    }
}

// ---------- fused pool selection: zero hists + score + 3-pass radix select ----------
__global__ void __launch_bounds__(256)
k_pool_select(const float* __restrict__ x, const float* __restrict__ p, int n, int k,
              float* __restrict__ score, int* __restrict__ selws,
              unsigned* __restrict__ prefix, int* __restrict__ rems,
              int* __restrict__ tiesN, unsigned* __restrict__ bar) {
    __shared__ int lh[2048];
    __shared__ int wsum[4];
    int tid = threadIdx.x;
    int lane = tid & 63, wid = tid >> 6;
    // zero hists (5120 ints)
    for (int i = blockIdx.x * 256 + tid; i < 5120; i += SELB * 256) selws[i] = 0;
    // scores (grid-stride; same per-node math as before)
    float pv0 = p[lane], pv1 = p[lane + 64];
    float ps = pv0 * pv0 + pv1 * pv1;
    #pragma unroll
    for (int off = 32; off > 0; off >>= 1) ps += __shfl_xor(ps, off);
    float rnorm = 1.0f / sqrtf(ps);
    for (int node = blockIdx.x * 4 + wid; node < n; node += SELB * 4) {
        const float* row = x + (size_t)node * HD;
        float s = row[lane] * pv0 + row[lane + 64] * pv1;
        #pragma unroll
        for (int off = 32; off > 0; off >>= 1) s += __shfl_xor(s, off);
        if (lane == 0) score[node] = tanhf(s * rnorm);
    }
    grid_barrier(bar, SELB);
    unsigned pfx = 0u;
    for (int pass = 0; pass < 3; ++pass) {
        int nbins = (pass == 2) ? 1024 : 2048;
        int* hist = selws + ((pass == 0) ? 0 : (pass == 1) ? 2048 : 4096);
        if (pass) pfx = __hip_atomic_load(prefix, __ATOMIC_RELAXED, __HIP_MEMORY_SCOPE_AGENT);
        for (int i = tid; i < nbins; i += 256) lh[i] = 0;
        __syncthreads();
        for (int i = blockIdx.x * 256 + tid; i < n; i += SELB * 256) {
            unsigned u = fenc(score[i]);
            int bin; bool ok;
            if (pass == 0)      { bin = u >> 21;          ok = true; }
            else if (pass == 1) { bin = (u >> 10) & 2047; ok = ((u >> 21) == (pfx >> 21)); }
            else                { bin = u & 1023;         ok = ((u >> 10) == (pfx >> 10)); }
            if (ok) atomicAdd(&lh[bin], 1);
        }
        __syncthreads();
        for (int i = tid; i < nbins; i += 256) {
            int c = lh[i];
            if (c) __hip_atomic_fetch_add(&hist[i], c, __ATOMIC_RELAXED, __HIP_MEMORY_SCOPE_AGENT);
        }
        grid_barrier(bar, SELB);
        if (blockIdx.x == 0) {
            int kk = (pass == 0) ? k : rems[pass - 1];
            int per = nbins >> 8;
            int hi = nbins - tid * per, lo = hi - per;
            int s = 0;
            for (int b = lo; b < hi; ++b)
                s += __hip_atomic_load(&hist[b], __ATOMIC_RELAXED, __HIP_MEMORY_SCOPE_AGENT);
            int x2 = s;
            #pragma unroll
            for (int off = 1; off < 64; off <<= 1) {
                int y = __shfl_up(x2, off);
                if (lane >= off) x2 += y;
            }
            if (lane == 63) wsum[wid] = x2;
            __syncthreads();
            int wb = 0;
            for (int w = 0; w < wid; ++w) wb += wsum[w];
            int excl = wb + x2 - s;
            if (kk > excl && kk <= excl + s) {
                int cum = excl;
                int shift = (pass == 0) ? 21 : (pass == 1) ? 10 : 0;
                for (int b = hi - 1; b >= lo; --b) {
                    int h = __hip_atomic_load(&hist[b], __ATOMIC_RELAXED, __HIP_MEMORY_SCOPE_AGENT);
                    if (kk <= cum + h) {
                        unsigned base2 = (pass == 0) ? 0u
                            : __hip_atomic_load(prefix, __ATOMIC_RELAXED, __HIP_MEMORY_SCOPE_AGENT);
                        __hip_atomic_store(prefix, base2 | ((unsigned)b << shift),
                                           __ATOMIC_RELAXED, __HIP_MEMORY_SCOPE_AGENT);
                        if (pass < 2) rems[pass] = kk - cum;
                        else tiesN[0] = kk - cum;
                        break;
                    }
                    cum += h;
                }
            }
            __syncthreads();
        }
        grid_barrier(bar, SELB);
    }
}

// ---------- fused deterministic compaction: count + scan + assign ----------
__global__ void __launch_bounds__(256)
k_pool_compact(const float* __restrict__ score, int n, int kcap,
               const unsigned* __restrict__ prefix, const int* __restrict__ tiesN,
               int* __restrict__ bgt, int* __restrict__ beq,
               int* __restrict__ pos, int* __restrict__ perm, float* __restrict__ vals,
               unsigned* __restrict__ bar) {
    int nb = gridDim.x;
    unsigned T = prefix[0];
    int tiesNeed = tiesN[0];
    int lane = threadIdx.x & 63, wid = threadIdx.x >> 6;
    int base = blockIdx.x * 1024;
    // phase 1: count
    {
        int gt = 0, eq = 0;
        #pragma unroll
        for (int it = 0; it < 4; ++it) {
            int i = base + it * 256 + threadIdx.x;
            if (i < n) {
                unsigned u = fenc(score[i]);
                gt += (u > T); eq += (u == T);
            }
        }
        __shared__ int sg[4], se[4];
        #pragma unroll
        for (int off = 32; off > 0; off >>= 1) { gt += __shfl_down(gt, off); eq += __shfl_down(eq, off); }
        if (lane == 0) { sg[wid] = gt; se[wid] = eq; }
        __syncthreads();
        if (threadIdx.x == 0) {
            bgt[blockIdx.x] = sg[0] + sg[1] + sg[2] + sg[3];
            beq[blockIdx.x] = se[0] + se[1] + se[2] + se[3];
        }
    }
    grid_barrier(bar, nb);
    if (blockIdx.x == 0 && threadIdx.x < 64) {
        int t = threadIdx.x;
        int va = (t < nb) ? bgt[t] : 0;
        int vb = (t < nb) ? beq[t] : 0;
        int xa = va, xb = vb;
        #pragma unroll
        for (int off = 1; off < 64; off <<= 1) {
            int ya = __shfl_up(xa, off), yb = __shfl_up(xb, off);
            if (t >= off) { xa += ya; xb += yb; }
        }
        if (t < nb) { bgt[t] = xa - va; beq[t] = xb - vb; }
    }
    grid_barrier(bar, nb);
    // phase 2: assign
    {
        __shared__ int wgt[4], weq[4];
        __shared__ int rgt, req;
        if (threadIdx.x == 0) { rgt = bgt[blockIdx.x]; req = beq[blockIdx.x]; }
        __syncthreads();
        #pragma unroll
        for (int it = 0; it < 4; ++it) {
            int i = base + it * 256 + threadIdx.x;
            bool in = i < n;
            float sc = in ? score[i] : 0.f;
            unsigned u = in ? fenc(sc) : 0u;
            bool g = in && (u > T);
            bool e = in && (u == T);
            unsigned long long mg = __ballot(g), me = __ballot(e);
            int lgt = __popcll(mg & ((1ull << lane) - 1ull));
            int leq = __popcll(me & ((1ull << lane) - 1ull));
            if (lane == 0) { wgt[wid] = __popcll(mg); weq[wid] = __popcll(me); }
            __syncthreads();
            int wbg = 0, wbe = 0;
            for (int w = 0; w < wid; ++w) { wbg += wgt[w]; wbe += weq[w]; }
            int gtRank = rgt + wbg + lgt;
            int tieRank = req + wbe + leq;
            if (in) {
                int slot = -1;
                if (g) slot = gtRank + min(tieRank, tiesNeed);
                else if (e && tieRank < tiesNeed) slot = gtRank + tieRank;
                if (slot >= kcap) slot = -1;
                pos[i] = slot;
                if (slot >= 0) { perm[slot] = i; vals[slot] = sc; }
            }
            __syncthreads();
            if (threadIdx.x == 0) {
                rgt += wgt[0] + wgt[1] + wgt[2] + wgt[3];
                req += weq[0] + weq[1] + weq[2] + weq[3];
            }
            __syncthreads();
        }
    }
}

// xp = x[perm] * vals, then BN  (fused)
__global__ void k_pool_bn(const float* __restrict__ x, const int* __restrict__ perm,
                          const float* __restrict__ vals, const float* __restrict__ g,
                          const float* __restrict__ b, float* __restrict__ out, int k) {
    int idx = blockIdx.x * 256 + threadIdx.x;
    if (idx >= k * HD) return;
    int slot = idx >> 7, c = idx & 127;
    int v = perm[slot];
    out[idx] = (x[(size_t)v * HD + c] * vals[slot]) * (g[c] * BN_SCALE) + b[c];
}

// ---------- fused edge compaction: zero-cnt + count + scan + assign ----------
__global__ void __launch_bounds__(256)
k_ecompact(const int* __restrict__ src, const int* __restrict__ dst,
           const float* __restrict__ w, const int* __restrict__ pos,
           const int* __restrict__ EinPtr, int EinImm, int kNodes,
           int* __restrict__ bsumE,
           int* __restrict__ nsrc, int* __restrict__ ndst, float* __restrict__ nw,
           int* __restrict__ cnt, int* __restrict__ ecntOut,
           unsigned* __restrict__ bar) {
    int Ein = EinPtr ? EinPtr[0] : EinImm;
    int nb = gridDim.x;
    int lane = threadIdx.x & 63, wid = threadIdx.x >> 6;
    int base = blockIdx.x * 1024;
    // phase 0: zero next-level degree counters
    for (int i = blockIdx.x * 256 + threadIdx.x; i < kNodes; i += nb * 256) cnt[i] = 0;
    grid_barrier(bar, nb);
    // phase 1: per-chunk valid count
    {
        int c = 0;
        #pragma unroll
        for (int it = 0; it < 4; ++it) {
            int e = base + it * 256 + threadIdx.x;
            if (e < Ein) {
                float wv = w[e];
                if (wv != 0.0f && pos[src[e]] >= 0 && pos[dst[e]] >= 0) ++c;
            }
        }
        __shared__ int ws4[4];
        #pragma unroll
        for (int off = 32; off > 0; off >>= 1) c += __shfl_down(c, off);
        if (lane == 0) ws4[wid] = c;
        __syncthreads();
        if (threadIdx.x == 0) bsumE[blockIdx.x] = ws4[0] + ws4[1] + ws4[2] + ws4[3];
    }
    grid_barrier(bar, nb);
    // phase 2: block 0 exclusive-scans bsumE[0..nb), nb <= 1024
    if (blockIdx.x == 0) {
        __shared__ int wtot[4];
        int t = threadIdx.x;
        int i0 = t * 4;
        int v0 = (i0 + 0 < nb) ? bsumE[i0 + 0] : 0;
        int v1 = (i0 + 1 < nb) ? bsumE[i0 + 1] : 0;
        int v2 = (i0 + 2 < nb) ? bsumE[i0 + 2] : 0;
        int v3 = (i0 + 3 < nb) ? bsumE[i0 + 3] : 0;
        int tot = v0 + v1 + v2 + v3;
        int x2 = tot;
        #pragma unroll
        for (int off = 1; off < 64; off <<= 1) {
            int y = __shfl_up(x2, off);
            if (lane >= off) x2 += y;
        }
        if (lane == 63) wtot[wid] = x2;
        __syncthreads();
        int wb = 0;
        for (int q = 0; q < wid; ++q) wb += wtot[q];
        int excl = wb + x2 - tot;
        if (i0 + 0 < nb) bsumE[i0 + 0] = excl;
        if (i0 + 1 < nb) bsumE[i0 + 1] = excl + v0;
        if (i0 + 2 < nb) bsumE[i0 + 2] = excl + v0 + v1;
        if (i0 + 3 < nb) bsumE[i0 + 3] = excl + v0 + v1 + v2;
        if (t == 255) ecntOut[0] = wtot[0] + wtot[1] + wtot[2] + wtot[3];
    }
    grid_barrier(bar, nb);
    // phase 3: assign + next-level degree counts
    {
        __shared__ int wcnt[4];
        __shared__ int running;
        if (threadIdx.x == 0) running = bsumE[blockIdx.x];
        __syncthreads();
        #pragma unroll
        for (int it = 0; it < 4; ++it) {
            int e = base + it * 256 + threadIdx.x;
            bool valid = false; int ns = 0, nd = 0; float wv = 0.f;
            if (e < Ein) {
                wv = w[e];
                if (wv != 0.0f) {
                    ns = pos[src[e]]; nd = pos[dst[e]];
                    valid = (ns >= 0) && (nd >= 0);
                }
            }
            unsigned long long m = __ballot(valid);
            int r = __popcll(m & ((1ull << lane) - 1ull));
            if (lane == 0) wcnt[wid] = __popcll(m);
            __syncthreads();
            int wb = 0;
            for (int w2 = 0; w2 < wid; ++w2) wb += wcnt[w2];
            if (valid) {
                int slot = running + wb + r;
                nsrc[slot] = ns; ndst[slot] = nd; nw[slot] = wv;
                atomicAdd(&cnt[nd], 1);
            }
            __syncthreads();
            if (threadIdx.x == 0) running += wcnt[0] + wcnt[1] + wcnt[2] + wcnt[3];
            __syncthreads();
        }
    }
}

// ---------- readout: two-phase column sum + fused final matvec/BN ----------
__global__ void __launch_bounds__(256)
k_colsum_part(const float* __restrict__ h, float* __restrict__ cpart, int n) {
    int c = threadIdx.x & 127;
    int rh = threadIdx.x >> 7;
    int r0 = blockIdx.x * 64;
    int r1 = min(n, r0 + 64);
    float local = 0.f;
    for (int r = r0 + rh; r < r1; r += 2) local += h[(size_t)r * HD + c];
    __shared__ float sh[256];
    sh[threadIdx.x] = local;
    __syncthreads();
    if (threadIdx.x < 128) cpart[(size_t)blockIdx.x * HD + c] = sh[c] + sh[c + 128];
}

__global__ void __launch_bounds__(1024)
k_colsum_final(const float* __restrict__ cpart, int nb,
               const float* __restrict__ Wr, const float* __restrict__ br,
               const float* __restrict__ gr, const float* __restrict__ brn,
               float* __restrict__ out) {
    __shared__ float gsh[HD];
    int c = threadIdx.x & 127;
    int seg = threadIdx.x >> 7;
    float local = 0.f;
    for (int b = seg; b < nb; b += 8) local += cpart[(size_t)b * HD + c];
    __shared__ float sh[1024];
    sh[threadIdx.x] = local;
    __syncthreads();
    if (threadIdx.x < 128) {
        float s = 0.f;
        #pragma unroll
        for (int q = 0; q < 8; ++q) s += sh[c + q * 128];
        gsh[c] = s;
    }
    __syncthreads();
    if (threadIdx.x < 128) {
        float s = br[c];
        for (int k = 0; k < HD; ++k) s += gsh[k] * Wr[k * HD + c];
        out[c] = s * (gr[c] * BN_SCALE) + brn[c];
    }
}

// ---------- orchestration ----------
extern "C" void kernel_launch(void* const* d_in, const int* in_sizes, int n_in,
                              void* d_out, int out_size, void* d_ws, size_t ws_size,
                              hipStream_t stream) {
    const float* x     = (const float*)d_in[0];
    const int*   ei    = (const int*)d_in[1];
    const float* eattr = (const float*)d_in[2];
    const float* We_w  = (const float*)d_in[3];
    const float* We_b  = (const float*)d_in[4];
    const float* Wdown = (const float*)d_in[5];
    const float* bdown = (const float*)d_in[6];
    const float* Wpool = (const float*)d_in[7];
    const float* Wup   = (const float*)d_in[8];
    const float* bup   = (const float*)d_in[9];
    const float* gnorm = (const float*)d_in[10];
    const float* bnorm = (const float*)d_in[11];
    const float* Wr    = (const float*)d_in[12];
    const float* br    = (const float*)d_in[13];
    const float* gr    = (const float*)d_in[14];
    const float* brn   = (const float*)d_in[15];
    const int* src0 = ei;
    const int* dst0 = ei + E0;
    float* out = (float*)d_out;

    char* p = (char*)d_ws;
    auto alloc = [&](size_t bytes) -> void* {
        void* r = (void*)p;
        p += (bytes + 255) & ~(size_t)255;
        return r;
    };
    float* ew0  = (float*)alloc(E0 * 4);
    int* src1 = (int*)alloc(E1C * 4); int* dst1 = (int*)alloc(E1C * 4); float* ew1 = (float*)alloc(E1C * 4);
    int* src2 = (int*)alloc(E2C * 4); int* dst2 = (int*)alloc(E2C * 4); float* ew2 = (float*)alloc(E2C * 4);
    int* src3 = (int*)alloc(E3C * 4); int* dst3 = (int*)alloc(E3C * 4); float* ew3 = (float*)alloc(E3C * 4);
    float* hbuf = (float*)alloc((size_t)N0 * HD * 4);
    float* hW   = (float*)alloc((size_t)N0 * HD * 4);
    float* tmp  = (float*)alloc((size_t)N0 * HD * 4);
    float* xs0  = (float*)alloc((size_t)N0 * HD * 4);
    float* xs1  = (float*)alloc((size_t)KP1 * HD * 4);
    float* xs2  = (float*)alloc((size_t)KP2 * HD * 4);
    float* deg   = (float*)alloc(N0 * 4);
    float* dinv  = (float*)alloc(N0 * 4);
    float* score = (float*)alloc(N0 * 4);
    int*   pos1  = (int*)alloc(N0 * 4);
    int*   pos2  = (int*)alloc(N0 * 4);
    int*   pos3  = (int*)alloc(N0 * 4);
    float* vals  = (float*)alloc(KP1 * 4);
    int* perm1 = (int*)alloc(KP1 * 4);
    int* perm2 = (int*)alloc(KP2 * 4);
    int* perm3 = (int*)alloc(KP3 * 4);
    int* rowptr0 = (int*)alloc((N0 + 1) * 4);
    int* rowptr1 = (int*)alloc((KP1 + 1) * 4);
    int* rowptr2 = (int*)alloc((KP2 + 1) * 4);
    int* rowptr3 = (int*)alloc((KP3 + 1) * 4);
    int2* csrP0 = (int2*)alloc((size_t)E0 * 8);
    int2* csrP1 = (int2*)alloc((size_t)E1C * 8);
    int2* csrP2 = (int2*)alloc((size_t)E2C * 8);
    int2* csrP3 = (int2*)alloc((size_t)E3C * 8);
    int* cnt    = (int*)alloc(N0 * 4);
    int* cursor = (int*)alloc(N0 * 4);
    int* selws  = (int*)alloc(5120 * 4);     // hist0|hist1|hist2
    int* bgt    = (int*)alloc(64 * 4);
    int* beq    = (int*)alloc(64 * 4);
    int* bsum   = (int*)alloc(64 * 4);
    int* bsumE  = (int*)alloc(1024 * 4);
    float2* partials = (float2*)alloc(((E0 + 255) / 256) * 8);
    float* cpart = (float*)alloc((size_t)CSB * HD * 4);
    float* mmv       = (float*)alloc(64);
    unsigned* barws  = (unsigned*)alloc(64 * 4);   // barSel|barCmp|barEco|dctrS
    unsigned* prefix = (unsigned*)alloc(64);
    int* rems        = (int*)alloc(64);            // rems[0..1]
    int* tiesN       = (int*)alloc(64);
    int* ecnt1       = (int*)alloc(64);
    int* ecnt2       = (int*)alloc(64);
    int* ecnt3       = (int*)alloc(64);
    unsigned* barSel = barws + 0;
    unsigned* barCmp = barws + 8;
    unsigned* barEco = barws + 16;
    unsigned* dctrS  = barws + 24;

    const int EB = (E0 + 255) / 256;

    auto build_csr = [&](const int* esrc, const int* edst, const float* eww, int n,
                         int* rowptr, int2* csrP,
                         const int* EinPtr, int EinImm, int gridE) {
        int nb = (n + 1023) / 1024;
        k_sum_scan<<<nb, 256, 0, stream>>>(cnt, bsum, n, rowptr + n, dctrS);
        k_chunk_scan<<<nb, 256, 0, stream>>>(cnt, bsum, rowptr, cursor, n);
        k_csr_fill<<<gridE, 256, 0, stream>>>(esrc, edst, eww, cursor, csrP, EinPtr, EinImm);
    };

    auto run_gcn = [&](const float* hin, const int* rowptr, const int2* csrP,
                       const float* W, const float* bias, float fill, int n, int lrelu,
                       float* outbuf, const float* bn_g, const float* bn_b,
                       const float* up_h, const int* up_pos) {
        k_gemm128<<<(n + GT_ROWS - 1) / GT_ROWS, 256, 0, stream>>>(hin, W, hW, n, bn_g, bn_b, up_h, up_pos);
        k_deg_dinv<<<(n + 255) / 256, 256, 0, stream>>>(rowptr, csrP, fill, deg, dinv, n);
        k_gcn_gather<<<(n + 3) / 4, 256, 0, stream>>>(rowptr, csrP, deg, dinv, hW,
                                                      bias, fill, n, lrelu, outbuf);
    };

    auto run_pool = [&](const float* xin, int n, int k, const float* pvec,
                        const float* g, const float* b,
                        const int* esrc_in, const int* edst_in, const float* ew_in,
                        const int* EinPtr, int EinImm,
                        int* pos, int* perm,
                        int* esrc_out, int* edst_out, float* ew_out, int* ecntOut) {
        int nb = (n + 1023) / 1024;
        k_pool_select<<<SELB, 256, 0, stream>>>(xin, pvec, n, k, score, selws, prefix, rems, tiesN, barSel);
        k_pool_compact<<<nb, 256, 0, stream>>>(score, n, k, prefix, tiesN, bgt, beq, pos, perm, vals, barCmp);
        k_pool_bn<<<((size_t)k * HD + 255) / 256, 256, 0, stream>>>(xin, perm, vals, g, b, hbuf, k);
        k_ecompact<<<NBE, 256, 0, stream>>>(esrc_in, edst_in, ew_in, pos, EinPtr, EinImm, k,
                                            bsumE, esrc_out, edst_out, ew_out, cnt, ecntOut, barEco);
    };

    // ---- init barrier words + level-0 degree counters ----
    hipMemsetAsync(barws, 0, 64 * 4, stream);
    hipMemsetAsync(cnt, 0, (size_t)N0 * 4, stream);

    // ---- edge weights + fused level-0 degree count ----
    k_edge_ew<<<EB, 256, 0, stream>>>(eattr, We_w, We_b, ew0, partials, E0);
    k_reduce_mm<<<1, 1024, 0, stream>>>(partials, EB, mmv);
    k_ew_norm_count<<<EB, 256, 0, stream>>>(ew0, mmv, dst0, cnt, E0);

    // ---- CSR level 0 ----
    build_csr(src0, dst0, ew0, N0, rowptr0, csrP0, (const int*)nullptr, E0, EB);

    // ---- level 0 (BN fused into GEMM A-staging) ----
    run_gcn(x, rowptr0, csrP0, Wdown, bdown, 1.0f, N0, 1, xs0, gnorm, bnorm, nullptr, nullptr);

    // ---- down: pool 1 / gcn 1 ----
    run_pool(xs0, N0, KP1, Wpool, gnorm + HD, bnorm + HD, src0, dst0, ew0,
             (const int*)nullptr, E0, pos1, perm1, src1, dst1, ew1, ecnt1);
    build_csr(src1, dst1, ew1, KP1, rowptr1, csrP1, ecnt1, 0, (E1C + 255) / 256);
    run_gcn(hbuf, rowptr1, csrP1, Wdown + 1 * HD * HD, bdown + 1 * HD, 1.0f, KP1, 1, xs1,
            nullptr, nullptr, nullptr, nullptr);

    // ---- down: pool 2 / gcn 2 ----
    run_pool(xs1, KP1, KP2, Wpool + HD, gnorm + 2 * HD, bnorm + 2 * HD, src1, dst1, ew1,
             ecnt1, 0, pos2, perm2, src2, dst2, ew2, ecnt2);
    build_csr(src2, dst2, ew2, KP2, rowptr2, csrP2, ecnt2, 0, (E2C + 255) / 256);
    run_gcn(hbuf, rowptr2, csrP2, Wdown + 2 * HD * HD, bdown + 2 * HD, 1.0f, KP2, 1, xs2,
            nullptr, nullptr, nullptr, nullptr);

    // ---- down: pool 3 / gcn 3 (no lrelu) ----
    run_pool(xs2, KP2, KP3, Wpool + 2 * HD, gnorm + 3 * HD, bnorm + 3 * HD, src2, dst2, ew2,
             ecnt2, 0, pos3, perm3, src3, dst3, ew3, ecnt3);
    build_csr(src3, dst3, ew3, KP3, rowptr3, csrP3, ecnt3, 0, (E3C + 255) / 256);
    run_gcn(hbuf, rowptr3, csrP3, Wdown + 3 * HD * HD, bdown + 3 * HD, 1.0f, KP3, 0, tmp,
            nullptr, nullptr, nullptr, nullptr);

    // ---- up 0: level 12500, CSR 2, fill=2 (unpool fused into GEMM) ----
    run_gcn(xs2, rowptr2, csrP2, Wup, bup, 2.0f, KP2, 1, tmp, nullptr, nullptr, tmp, pos3);

    // ---- up 1: level 25000, CSR 1 ----
    run_gcn(xs1, rowptr1, csrP1, Wup + 1 * HD * HD, bup + 1 * HD, 2.0f, KP1, 1, tmp,
            nullptr, nullptr, tmp, pos2);

    // ---- up 2: level 50000, CSR 0 (no lrelu) ----
    run_gcn(xs0, rowptr0, csrP0, Wup + 2 * HD * HD, bup + 2 * HD, 2.0f, N0, 0, tmp,
            nullptr, nullptr, tmp, pos1);

    // ---- readout (two-phase colsum + fused final) ----
    k_colsum_part<<<CSB, 256, 0, stream>>>(tmp, cpart, N0);
    k_colsum_final<<<1, 1024, 0, stream>>>(cpart, CSB, Wr, br, gr, brn, out);
}

// Round 9
// 934.068 us; speedup vs baseline: 2.1475x; 2.1475x over previous
//
#include <hip/hip_runtime.h>
#include <math.h>

// Problem constants (from reference)
#define N0   50000
#define E0   800000
#define HD   128          // D == H == 128
#define EHD  16
#define KP1  25000
#define KP2  12500
#define KP3  6250
#define BN_SCALE 0.9999950000374997f   // 1/sqrt(1+1e-5)
#define NEG_SLOPE 0.01f
// compacted-edge capacity per level (expected E/4^i, wide margin; inputs are fixed seed)
#define E1C  400000
#define E2C  120000
#define E3C  40000
#define NBE  782          // ceil(E0/1024)
#define CSB  782          // colsum phase-1 blocks

// ---------- helpers ----------
__device__ __forceinline__ unsigned fenc(float f) {
    unsigned u = __float_as_uint(f);
    return (u & 0x80000000u) ? ~u : (u | 0x80000000u);
}

// ---------- edge embedding: per-block partial min/max ----------
__global__ void k_edge_ew(const float* __restrict__ ea, const float* __restrict__ Ww,
                          const float* __restrict__ Wb, float* __restrict__ ew,
                          float2* __restrict__ partials, int E) {
    int e = blockIdx.x * 256 + threadIdx.x;
    float mn = 3.4e38f, mx = -3.4e38f;
    if (e < E) {
        const float4* a4 = (const float4*)(ea + (size_t)e * EHD);
        float s = Wb[0];
        #pragma unroll
        for (int q = 0; q < 4; ++q) {
            float4 a = a4[q];
            s += a.x * Ww[q*4+0] + a.y * Ww[q*4+1] + a.z * Ww[q*4+2] + a.w * Ww[q*4+3];
        }
        ew[e] = s;
        mn = s; mx = s;
    }
    #pragma unroll
    for (int off = 32; off > 0; off >>= 1) {
        mn = fminf(mn, __shfl_xor(mn, off));
        mx = fmaxf(mx, __shfl_xor(mx, off));
    }
    __shared__ float smn[4], smx[4];
    int lane = threadIdx.x & 63, wid = threadIdx.x >> 6;
    if (lane == 0) { smn[wid] = mn; smx[wid] = mx; }
    __syncthreads();
    if (threadIdx.x == 0) {
        float a = fminf(fminf(smn[0], smn[1]), fminf(smn[2], smn[3]));
        float b = fmaxf(fmaxf(smx[0], smx[1]), fmaxf(smx[2], smx[3]));
        partials[blockIdx.x] = make_float2(a, b);
    }
}

__global__ void __launch_bounds__(1024)
k_reduce_mm(const float2* __restrict__ partials, int nb, float* __restrict__ mmv) {
    float mn = 3.4e38f, mx = -3.4e38f;
    for (int i = threadIdx.x; i < nb; i += 1024) {
        float2 t = partials[i];
        mn = fminf(mn, t.x); mx = fmaxf(mx, t.y);
    }
    #pragma unroll
    for (int off = 32; off > 0; off >>= 1) {
        mn = fminf(mn, __shfl_xor(mn, off));
        mx = fmaxf(mx, __shfl_xor(mx, off));
    }
    __shared__ float smn[16], smx[16];
    int lane = threadIdx.x & 63, wid = threadIdx.x >> 6;
    if (lane == 0) { smn[wid] = mn; smx[wid] = mx; }
    __syncthreads();
    if (threadIdx.x == 0) {
        for (int w = 1; w < 16; ++w) { mn = fminf(mn, smn[w]); mx = fmaxf(mx, smx[w]); }
        mmv[0] = mn; mmv[1] = mx;
    }
}

// normalize + fused level-0 CSR degree count (cnt must be zeroed)
__global__ void k_ew_norm_count(float* __restrict__ ew, const float* __restrict__ mmv,
                                const int* __restrict__ dst, int* __restrict__ cnt, int E) {
    int e = blockIdx.x * 256 + threadIdx.x;
    if (e >= E) return;
    float mn = mmv[0];
    float sc = 1.0f / ((mmv[1] - mn) + 1e-7f);
    float w = (ew[e] - mn) * sc;
    ew[e] = w;
    if (w != 0.0f) atomicAdd(&cnt[dst[e]], 1);
}

// ---------- n x 128 @ 128 x 128 GEMM, fused optional BN / unpool-scatter on A ----------
#define GT_ROWS 64
__global__ void __launch_bounds__(256)
k_gemm128(const float* __restrict__ A, const float* __restrict__ W,
          float* __restrict__ C, int n,
          const float* __restrict__ gs, const float* __restrict__ gb,
          const float* __restrict__ up_h, const int* __restrict__ up_pos) {
    __shared__ float As[GT_ROWS][132];   // +4 pad
    int tid = threadIdx.x;               // 256
    int row0 = blockIdx.x * GT_ROWS;
    int maxr = n - row0;
    {
        #pragma unroll
        for (int it = 0; it < 8; ++it) {
            int idx = it * 256 + tid;
            int r = idx >> 5, q = idx & 31;
            float4 v = make_float4(0.f, 0.f, 0.f, 0.f);
            if (r < maxr) {
                v = ((const float4*)(A + (size_t)(row0 + r) * HD))[q];
                if (up_pos) {
                    int sl = up_pos[row0 + r];
                    if (sl >= 0) {
                        float4 u = ((const float4*)(up_h + (size_t)sl * HD))[q];
                        v.x += u.x; v.y += u.y; v.z += u.z; v.w += u.w;
                    }
                }
                if (gs) {
                    float4 g4 = ((const float4*)gs)[q];
                    float4 b4 = ((const float4*)gb)[q];
                    v.x = v.x * (g4.x * BN_SCALE) + b4.x;
                    v.y = v.y * (g4.y * BN_SCALE) + b4.y;
                    v.z = v.z * (g4.z * BN_SCALE) + b4.z;
                    v.w = v.w * (g4.w * BN_SCALE) + b4.w;
                }
            }
            *(float4*)&As[r][q * 4] = v;
        }
    }
    __syncthreads();
    int cg = tid & 31;
    int rg = tid >> 5;
    float4 acc[8];
    #pragma unroll
    for (int j = 0; j < 8; ++j) acc[j] = make_float4(0.f, 0.f, 0.f, 0.f);
    const float4* W4 = (const float4*)W;
    #pragma unroll 4
    for (int k = 0; k < HD; k += 4) {
        float4 w0 = W4[(k + 0) * 32 + cg];
        float4 w1 = W4[(k + 1) * 32 + cg];
        float4 w2 = W4[(k + 2) * 32 + cg];
        float4 w3 = W4[(k + 3) * 32 + cg];
        #pragma unroll
        for (int jj = 0; jj < 4; ++jj) {
            float4 a = *(const float4*)&As[4 * rg + jj][k];
            acc[jj].x += a.x * w0.x + a.y * w1.x + a.z * w2.x + a.w * w3.x;
            acc[jj].y += a.x * w0.y + a.y * w1.y + a.z * w2.y + a.w * w3.y;
            acc[jj].z += a.x * w0.z + a.y * w1.z + a.z * w2.z + a.w * w3.z;
            acc[jj].w += a.x * w0.w + a.y * w1.w + a.z * w2.w + a.w * w3.w;
        }
        #pragma unroll
        for (int jj = 0; jj < 4; ++jj) {
            float4 a = *(const float4*)&As[32 + 4 * rg + jj][k];
            acc[4 + jj].x += a.x * w0.x + a.y * w1.x + a.z * w2.x + a.w * w3.x;
            acc[4 + jj].y += a.x * w0.y + a.y * w1.y + a.z * w2.y + a.w * w3.y;
            acc[4 + jj].z += a.x * w0.z + a.y * w1.z + a.z * w2.z + a.w * w3.z;
            acc[4 + jj].w += a.x * w0.w + a.y * w1.w + a.z * w2.w + a.w * w3.w;
        }
    }
    #pragma unroll
    for (int jj = 0; jj < 4; ++jj) {
        int r = 4 * rg + jj;
        if (r < maxr) *(float4*)&C[(size_t)(row0 + r) * HD + 4 * cg] = acc[jj];
    }
    #pragma unroll
    for (int jj = 0; jj < 4; ++jj) {
        int r = 32 + 4 * rg + jj;
        if (r < maxr) *(float4*)&C[(size_t)(row0 + r) * HD + 4 * cg] = acc[4 + jj];
    }
}

// ---------- CSR build: fused chunk-sum + block-scan (done-counter, self-resetting) ----------
__global__ void k_sum_scan(const int* __restrict__ cnt, int* __restrict__ bsum, int n,
                           int* __restrict__ totalOut, unsigned* __restrict__ dctr) {
    int base = blockIdx.x * 1024;
    int s = 0;
    #pragma unroll
    for (int it = 0; it < 4; ++it) {
        int i = base + it * 256 + threadIdx.x;
        if (i < n) s += cnt[i];
    }
    __shared__ int ws[4];
    __shared__ int lastFlag;
    int lane = threadIdx.x & 63, wid = threadIdx.x >> 6;
    #pragma unroll
    for (int off = 32; off > 0; off >>= 1) s += __shfl_down(s, off);
    if (lane == 0) ws[wid] = s;
    __syncthreads();
    if (threadIdx.x == 0) {
        __hip_atomic_store(&bsum[blockIdx.x], ws[0] + ws[1] + ws[2] + ws[3],
                           __ATOMIC_RELAXED, __HIP_MEMORY_SCOPE_AGENT);
        unsigned prev = __hip_atomic_fetch_add(dctr, 1u, __ATOMIC_ACQ_REL, __HIP_MEMORY_SCOPE_AGENT);
        lastFlag = (prev == gridDim.x - 1);
    }
    __syncthreads();
    if (!lastFlag) return;
    if (threadIdx.x < 64) {
        int nb = gridDim.x;
        int t = threadIdx.x;
        int v = (t < nb) ? __hip_atomic_load(&bsum[t], __ATOMIC_RELAXED, __HIP_MEMORY_SCOPE_AGENT) : 0;
        int x = v;
        #pragma unroll
        for (int off = 1; off < 64; off <<= 1) {
            int y = __shfl_up(x, off);
            if (t >= off) x += y;
        }
        if (t < nb) bsum[t] = x - v;
        if (t == nb - 1) totalOut[0] = x;
    }
    if (threadIdx.x == 0)
        __hip_atomic_store(dctr, 0u, __ATOMIC_RELAXED, __HIP_MEMORY_SCOPE_AGENT);
}

__global__ void k_chunk_scan(const int* __restrict__ cnt, const int* __restrict__ bo,
                             int* __restrict__ rowptr, int* __restrict__ cursor, int n) {
    __shared__ int wsum[4];
    __shared__ int running;
    int base = blockIdx.x * 1024;
    if (threadIdx.x == 0) running = bo[blockIdx.x];
    __syncthreads();
    int lane = threadIdx.x & 63, wid = threadIdx.x >> 6;
    #pragma unroll
    for (int it = 0; it < 4; ++it) {
        int i = base + it * 256 + threadIdx.x;
        int v = (i < n) ? cnt[i] : 0;
        int x = v;
        #pragma unroll
        for (int off = 1; off < 64; off <<= 1) {
            int y = __shfl_up(x, off);
            if (lane >= off) x += y;
        }
        if (lane == 63) wsum[wid] = x;
        __syncthreads();
        int wb = 0;
        for (int w = 0; w < wid; ++w) wb += wsum[w];
        int excl = running + wb + x - v;
        if (i < n) { rowptr[i] = excl; cursor[i] = excl; }
        __syncthreads();
        if (threadIdx.x == 0) running += wsum[0] + wsum[1] + wsum[2] + wsum[3];
        __syncthreads();
    }
}

// packed CSR entry: {src, float_bits(w)} — one 8B store per edge (halves write-amp)
__global__ void k_csr_fill(const int* __restrict__ src, const int* __restrict__ dst,
                           const float* __restrict__ w, int* __restrict__ cursor,
                           int2* __restrict__ csr,
                           const int* __restrict__ EinPtr, int EinImm) {
    int Ein = EinPtr ? EinPtr[0] : EinImm;
    int e = blockIdx.x * 256 + threadIdx.x;
    if (e >= Ein) return;
    float wv = w[e];
    if (wv == 0.0f) return;
    int slot = atomicAdd(&cursor[dst[e]], 1);
    csr[slot] = make_int2(src[e], __float_as_int(wv));
}

// ---------- degree from CSR ----------
__global__ void k_deg_dinv(const int* __restrict__ rowptr, const int2* __restrict__ csr,
                           float fill, float* __restrict__ deg, float* __restrict__ dinv, int n) {
    int v = blockIdx.x * 256 + threadIdx.x;
    if (v >= n) return;
    float s = fill;
    int rs = rowptr[v], re = rowptr[v + 1];
    for (int j = rs; j < re; ++j) s += __int_as_float(csr[j].y);
    deg[v] = s;
    dinv[v] = rsqrtf(s);
}

// ---------- fused GCN gather: 2 neighbors/wave, float4/lane, 4x unroll ----------
__global__ void __launch_bounds__(256)
k_gcn_gather(const int* __restrict__ rowptr, const int2* __restrict__ csr,
             const float* __restrict__ deg, const float* __restrict__ dinv,
             const float* __restrict__ hW, const float* __restrict__ bias,
             float fill, int n, int lrelu, float* __restrict__ out) {
    int v = blockIdx.x * 4 + (threadIdx.x >> 6);
    int lane = threadIdx.x & 63;
    if (v >= n) return;
    int rs = rowptr[v], re = rowptr[v + 1];
    float dv = dinv[v];
    int half = lane >> 5;
    int qi = lane & 31;
    float4 acc = make_float4(0.f, 0.f, 0.f, 0.f);
    for (int base = rs; base < re; base += 64) {
        int idx = base + lane;
        int s_r = 0; float c_r = 0.f;
        if (idx < re) {
            int2 ent = csr[idx];
            s_r = ent.x;
            c_r = dinv[s_r] * __int_as_float(ent.y) * dv;
        }
        int cnt = min(64, re - base);
        int pairs = cnt >> 1;
        int t = 0;
        for (; t + 3 < pairs; t += 4) {
            int j0 = 2 * t + half, j1 = j0 + 2, j2 = j0 + 4, j3 = j0 + 6;
            int   s0 = __shfl(s_r, j0); float c0 = __shfl(c_r, j0);
            int   s1 = __shfl(s_r, j1); float c1 = __shfl(c_r, j1);
            int   s2 = __shfl(s_r, j2); float c2 = __shfl(c_r, j2);
            int   s3 = __shfl(s_r, j3); float c3 = __shfl(c_r, j3);
            float4 h0 = ((const float4*)(hW + (size_t)s0 * HD))[qi];
            float4 h1 = ((const float4*)(hW + (size_t)s1 * HD))[qi];
            float4 h2 = ((const float4*)(hW + (size_t)s2 * HD))[qi];
            float4 h3 = ((const float4*)(hW + (size_t)s3 * HD))[qi];
            acc.x += c0 * h0.x; acc.y += c0 * h0.y; acc.z += c0 * h0.z; acc.w += c0 * h0.w;
            acc.x += c1 * h1.x; acc.y += c1 * h1.y; acc.z += c1 * h1.z; acc.w += c1 * h1.w;
            acc.x += c2 * h2.x; acc.y += c2 * h2.y; acc.z += c2 * h2.z; acc.w += c2 * h2.w;
            acc.x += c3 * h3.x; acc.y += c3 * h3.y; acc.z += c3 * h3.z; acc.w += c3 * h3.w;
        }
        for (; t < pairs; ++t) {
            int j = 2 * t + half;
            int s = __shfl(s_r, j); float c = __shfl(c_r, j);
            float4 h0 = ((const float4*)(hW + (size_t)s * HD))[qi];
            acc.x += c * h0.x; acc.y += c * h0.y; acc.z += c * h0.z; acc.w += c * h0.w;
        }
        if (cnt & 1) {
            int j = cnt - 1;
            int s = __shfl(s_r, j); float c = __shfl(c_r, j);
            if (half == 0) {
                float4 h0 = ((const float4*)(hW + (size_t)s * HD))[qi];
                acc.x += c * h0.x; acc.y += c * h0.y; acc.z += c * h0.z; acc.w += c * h0.w;
            }
        }
    }
    acc.x += __shfl_xor(acc.x, 32);
    acc.y += __shfl_xor(acc.y, 32);
    acc.z += __shfl_xor(acc.z, 32);
    acc.w += __shfl_xor(acc.w, 32);
    if (half == 0) {
        float4 hs = ((const float4*)(hW + (size_t)v * HD))[qi];
        float sc = fill / deg[v];
        float4 b4 = ((const float4*)bias)[qi];
        float4 o;
        o.x = acc.x + sc * hs.x + b4.x;
        o.y = acc.y + sc * hs.y + b4.y;
        o.z = acc.z + sc * hs.z + b4.z;
        o.w = acc.w + sc * hs.w + b4.w;
        if (lrelu) {
            o.x = o.x > 0.f ? o.x : NEG_SLOPE * o.x;
            o.y = o.y > 0.f ? o.y : NEG_SLOPE * o.y;
            o.z = o.z > 0.f ? o.z : NEG_SLOPE * o.z;
            o.w = o.w > 0.f ? o.w : NEG_SLOPE * o.w;
        }
        ((float4*)(out + (size_t)v * HD))[qi] = o;
    }
}

// ---------- TopK pooling ----------
__global__ void k_score(const float* __restrict__ x, const float* __restrict__ p,
                        float* __restrict__ score, int n) {
    int lane = threadIdx.x & 63;
    float pv0 = p[lane], pv1 = p[lane + 64];
    float ps = pv0 * pv0 + pv1 * pv1;
    #pragma unroll
    for (int off = 32; off > 0; off >>= 1) ps += __shfl_xor(ps, off);
    float rnorm = 1.0f / sqrtf(ps);
    int node = blockIdx.x * 4 + (threadIdx.x >> 6);
    if (node >= n) return;
    const float* row = x + (size_t)node * HD;
    float s = row[lane] * pv0 + row[lane + 64] * pv1;
    #pragma unroll
    for (int off = 32; off > 0; off >>= 1) s += __shfl_xor(s, off);
    if (lane == 0) score[node] = tanhf(s * rnorm);
}

// fused hist pass + last-block pick (done-counter pattern — proven in R7)
__global__ void __launch_bounds__(256)
k_histpick(const float* __restrict__ score, int n, int pass,
           unsigned* __restrict__ prefix, int* __restrict__ hist,
           int kImm, const int* __restrict__ remIn, int* __restrict__ remOut,
           unsigned* __restrict__ doneCtr) {
    __shared__ int lh[2048];
    int nbins = (pass == 2) ? 1024 : 2048;
    for (int i = threadIdx.x; i < nbins; i += 256) lh[i] = 0;
    __syncthreads();
    unsigned pfx = (pass != 0) ? prefix[0] : 0u;
    int stride = gridDim.x * 256;
    for (int i = blockIdx.x * 256 + threadIdx.x; i < n; i += stride) {
        unsigned u = fenc(score[i]);
        int bin; bool ok;
        if (pass == 0)      { bin = u >> 21;            ok = true; }
        else if (pass == 1) { bin = (u >> 10) & 2047;   ok = ((u >> 21) == (pfx >> 21)); }
        else                { bin = u & 1023;           ok = ((u >> 10) == (pfx >> 10)); }
        if (ok) atomicAdd(&lh[bin], 1);
    }
    __syncthreads();
    for (int i = threadIdx.x; i < nbins; i += 256) {
        int c = lh[i];
        if (c) __hip_atomic_fetch_add(&hist[i], c, __ATOMIC_RELAXED, __HIP_MEMORY_SCOPE_AGENT);
    }
    __syncthreads();
    __shared__ int lastFlag;
    if (threadIdx.x == 0) {
        unsigned prev = __hip_atomic_fetch_add(doneCtr, 1u, __ATOMIC_ACQ_REL, __HIP_MEMORY_SCOPE_AGENT);
        lastFlag = (prev == gridDim.x - 1);
    }
    __syncthreads();
    if (!lastFlag) return;
    __shared__ int wsum[4];
    int k = remIn ? remIn[0] : kImm;
    int t = threadIdx.x;
    int per = nbins >> 8;
    int hi = nbins - t * per, lo = hi - per;
    int s = 0;
    for (int b = lo; b < hi; ++b)
        s += __hip_atomic_load(&hist[b], __ATOMIC_RELAXED, __HIP_MEMORY_SCOPE_AGENT);
    int lane = t & 63, wid = t >> 6;
    int x = s;
    #pragma unroll
    for (int off = 1; off < 64; off <<= 1) {
        int y = __shfl_up(x, off);
        if (lane >= off) x += y;
    }
    if (lane == 63) wsum[wid] = x;
    __syncthreads();
    int wb = 0;
    for (int w = 0; w < wid; ++w) wb += wsum[w];
    int excl = wb + x - s;
    if (k > excl && k <= excl + s) {
        int cum = excl;
        int shift = (pass == 0) ? 21 : (pass == 1) ? 10 : 0;
        for (int b = hi - 1; b >= lo; --b) {
            int h = __hip_atomic_load(&hist[b], __ATOMIC_RELAXED, __HIP_MEMORY_SCOPE_AGENT);
            if (k <= cum + h) {
                unsigned base = (pass == 0) ? 0u : prefix[0];
                prefix[0] = base | ((unsigned)b << shift);
                remOut[0] = k - cum;
                break;
            }
            cum += h;
        }
    }
}

// ---------- parallel deterministic compaction of kept nodes ----------
__global__ void k_cmp_count(const float* __restrict__ score, int n,
                            const unsigned* __restrict__ prefix,
                            int* __restrict__ bgt, int* __restrict__ beq) {
    unsigned T = prefix[0];
    int base = blockIdx.x * 1024;
    int gt = 0, eq = 0;
    #pragma unroll
    for (int it = 0; it < 4; ++it) {
        int i = base + it * 256 + threadIdx.x;
        if (i < n) {
            unsigned u = fenc(score[i]);
            gt += (u > T); eq += (u == T);
        }
    }
    __shared__ int sg[4], se[4];
    int lane = threadIdx.x & 63, wid = threadIdx.x >> 6;
    #pragma unroll
    for (int off = 32; off > 0; off >>= 1) { gt += __shfl_down(gt, off); eq += __shfl_down(eq, off); }
    if (lane == 0) { sg[wid] = gt; se[wid] = eq; }
    __syncthreads();
    if (threadIdx.x == 0) {
        bgt[blockIdx.x] = sg[0] + sg[1] + sg[2] + sg[3];
        beq[blockIdx.x] = se[0] + se[1] + se[2] + se[3];
    }
}

__global__ void k_scan_blocks2(int* __restrict__ a, int* __restrict__ b, int nb) {
    int t = threadIdx.x;  // 64
    int va = (t < nb) ? a[t] : 0;
    int vb = (t < nb) ? b[t] : 0;
    int xa = va, xb = vb;
    #pragma unroll
    for (int off = 1; off < 64; off <<= 1) {
        int ya = __shfl_up(xa, off), yb = __shfl_up(xb, off);
        if (t >= off) { xa += ya; xb += yb; }
    }
    if (t < nb) { a[t] = xa - va; b[t] = xb - vb; }
}

__global__ void k_cmp_assign(const float* __restrict__ score, int n, int kcap,
                             const unsigned* __restrict__ prefix,
                             const int* __restrict__ selTies,
                             const int* __restrict__ bgt, const int* __restrict__ beq,
                             int* __restrict__ pos, int* __restrict__ perm,
                             float* __restrict__ vals) {
    unsigned T = prefix[0];
    int tiesNeed = selTies[0];
    __shared__ int wgt[4], weq[4];
    __shared__ int rgt, req;
    int base = blockIdx.x * 1024;
    if (threadIdx.x == 0) { rgt = bgt[blockIdx.x]; req = beq[blockIdx.x]; }
    __syncthreads();
    int lane = threadIdx.x & 63, wid = threadIdx.x >> 6;
    #pragma unroll
    for (int it = 0; it < 4; ++it) {
        int i = base + it * 256 + threadIdx.x;
        bool in = i < n;
        float sc = in ? score[i] : 0.f;
        unsigned u = in ? fenc(sc) : 0u;
        bool g = in && (u > T);
        bool e = in && (u == T);
        unsigned long long mg = __ballot(g), me = __ballot(e);
        int lgt = __popcll(mg & ((1ull << lane) - 1ull));
        int leq = __popcll(me & ((1ull << lane) - 1ull));
        if (lane == 0) { wgt[wid] = __popcll(mg); weq[wid] = __popcll(me); }
        __syncthreads();
        int wbg = 0, wbe = 0;
        for (int w = 0; w < wid; ++w) { wbg += wgt[w]; wbe += weq[w]; }
        int gtRank = rgt + wbg + lgt;
        int tieRank = req + wbe + leq;
        if (in) {
            int slot = -1;
            if (g) slot = gtRank + min(tieRank, tiesNeed);
            else if (e && tieRank < tiesNeed) slot = gtRank + tieRank;
            if (slot >= kcap) slot = -1;
            pos[i] = slot;
            if (slot >= 0) { perm[slot] = i; vals[slot] = sc; }
        }
        __syncthreads();
        if (threadIdx.x == 0) {
            rgt += wgt[0] + wgt[1] + wgt[2] + wgt[3];
            req += weq[0] + weq[1] + weq[2] + weq[3];
        }
        __syncthreads();
    }
}

// xp = x[perm] * vals, then BN  (fused)
__global__ void k_pool_bn(const float* __restrict__ x, const int* __restrict__ perm,
                          const float* __restrict__ vals, const float* __restrict__ g,
                          const float* __restrict__ b, float* __restrict__ out, int k) {
    int idx = blockIdx.x * 256 + threadIdx.x;
    if (idx >= k * HD) return;
    int slot = idx >> 7, c = idx & 127;
    int v = perm[slot];
    out[idx] = (x[(size_t)v * HD + c] * vals[slot]) * (g[c] * BN_SCALE) + b[c];
}

// ---------- edge compaction (3-phase, deterministic, separate kernels) ----------
__global__ void k_ecompact_count(const int* __restrict__ src, const int* __restrict__ dst,
                                 const float* __restrict__ w, const int* __restrict__ pos,
                                 const int* __restrict__ EinPtr, int EinImm,
                                 int* __restrict__ bsumE) {
    int Ein = EinPtr ? EinPtr[0] : EinImm;
    int base = blockIdx.x * 1024;
    int c = 0;
    #pragma unroll
    for (int it = 0; it < 4; ++it) {
        int e = base + it * 256 + threadIdx.x;
        if (e < Ein) {
            float wv = w[e];
            if (wv != 0.0f && pos[src[e]] >= 0 && pos[dst[e]] >= 0) ++c;
        }
    }
    __shared__ int ws[4];
    int lane = threadIdx.x & 63, wid = threadIdx.x >> 6;
    #pragma unroll
    for (int off = 32; off > 0; off >>= 1) c += __shfl_down(c, off);
    if (lane == 0) ws[wid] = c;
    __syncthreads();
    if (threadIdx.x == 0) bsumE[blockIdx.x] = ws[0] + ws[1] + ws[2] + ws[3];
}

// exclusive scan of a[0..nb), nb <= 1024, single block
__global__ void __launch_bounds__(1024)
k_scan1024(int* __restrict__ a, int nb, int* __restrict__ totalOut) {
    __shared__ int wsums[16];
    int t = threadIdx.x;
    int v = (t < nb) ? a[t] : 0;
    int lane = t & 63, wid = t >> 6;
    int x = v;
    #pragma unroll
    for (int off = 1; off < 64; off <<= 1) {
        int y = __shfl_up(x, off);
        if (lane >= off) x += y;
    }
    if (lane == 63) wsums[wid] = x;
    __syncthreads();
    int wb = 0;
    for (int w = 0; w < wid; ++w) wb += wsums[w];
    if (t < nb) a[t] = wb + x - v;
    if (t == 1023 && totalOut) {
        int tot = 0;
        for (int w = 0; w < 16; ++w) tot += wsums[w];
        totalOut[0] = tot;
    }
}

__global__ void k_ecompact_assign(const int* __restrict__ src, const int* __restrict__ dst,
                                  const float* __restrict__ w, const int* __restrict__ pos,
                                  const int* __restrict__ EinPtr, int EinImm,
                                  const int* __restrict__ bsumE,
                                  int* __restrict__ nsrc, int* __restrict__ ndst,
                                  float* __restrict__ nw, int* __restrict__ cnt) {
    int Ein = EinPtr ? EinPtr[0] : EinImm;
    __shared__ int wcnt[4];
    __shared__ int running;
    if (threadIdx.x == 0) running = bsumE[blockIdx.x];
    __syncthreads();
    int base = blockIdx.x * 1024;
    int lane = threadIdx.x & 63, wid = threadIdx.x >> 6;
    #pragma unroll
    for (int it = 0; it < 4; ++it) {
        int e = base + it * 256 + threadIdx.x;
        bool valid = false; int ns = 0, nd = 0; float wv = 0.f;
        if (e < Ein) {
            wv = w[e];
            if (wv != 0.0f) {
                ns = pos[src[e]]; nd = pos[dst[e]];
                valid = (ns >= 0) && (nd >= 0);
            }
        }
        unsigned long long m = __ballot(valid);
        int r = __popcll(m & ((1ull << lane) - 1ull));
        if (lane == 0) wcnt[wid] = __popcll(m);
        __syncthreads();
        int wb = 0;
        for (int w2 = 0; w2 < wid; ++w2) wb += wcnt[w2];
        if (valid) {
            int slot = running + wb + r;
            nsrc[slot] = ns; ndst[slot] = nd; nw[slot] = wv;
            atomicAdd(&cnt[nd], 1);
        }
        __syncthreads();
        if (threadIdx.x == 0) running += wcnt[0] + wcnt[1] + wcnt[2] + wcnt[3];
        __syncthreads();
    }
}

// ---------- readout: two-phase column sum + fused final matvec/BN ----------
__global__ void __launch_bounds__(256)
k_colsum_part(const float* __restrict__ h, float* __restrict__ cpart, int n) {
    int c = threadIdx.x & 127;
    int rh = threadIdx.x >> 7;
    int r0 = blockIdx.x * 64;
    int r1 = min(n, r0 + 64);
    float local = 0.f;
    for (int r = r0 + rh; r < r1; r += 2) local += h[(size_t)r * HD + c];
    __shared__ float sh[256];
    sh[threadIdx.x] = local;
    __syncthreads();
    if (threadIdx.x < 128) cpart[(size_t)blockIdx.x * HD + c] = sh[c] + sh[c + 128];
}

__global__ void __launch_bounds__(1024)
k_colsum_final(const float* __restrict__ cpart, int nb,
               const float* __restrict__ Wr, const float* __restrict__ br,
               const float* __restrict__ gr, const float* __restrict__ brn,
               float* __restrict__ out) {
    __shared__ float gsh[HD];
    int c = threadIdx.x & 127;
    int seg = threadIdx.x >> 7;
    float local = 0.f;
    for (int b = seg; b < nb; b += 8) local += cpart[(size_t)b * HD + c];
    __shared__ float sh[1024];
    sh[threadIdx.x] = local;
    __syncthreads();
    if (threadIdx.x < 128) {
        float s = 0.f;
        #pragma unroll
        for (int q = 0; q < 8; ++q) s += sh[c + q * 128];
        gsh[c] = s;
    }
    __syncthreads();
    if (threadIdx.x < 128) {
        float s = br[c];
        for (int k = 0; k < HD; ++k) s += gsh[k] * Wr[k * HD + c];
        out[c] = s * (gr[c] * BN_SCALE) + brn[c];
    }
}

// ---------- orchestration ----------
extern "C" void kernel_launch(void* const* d_in, const int* in_sizes, int n_in,
                              void* d_out, int out_size, void* d_ws, size_t ws_size,
                              hipStream_t stream) {
    const float* x     = (const float*)d_in[0];
    const int*   ei    = (const int*)d_in[1];
    const float* eattr = (const float*)d_in[2];
    const float* We_w  = (const float*)d_in[3];
    const float* We_b  = (const float*)d_in[4];
    const float* Wdown = (const float*)d_in[5];
    const float* bdown = (const float*)d_in[6];
    const float* Wpool = (const float*)d_in[7];
    const float* Wup   = (const float*)d_in[8];
    const float* bup   = (const float*)d_in[9];
    const float* gnorm = (const float*)d_in[10];
    const float* bnorm = (const float*)d_in[11];
    const float* Wr    = (const float*)d_in[12];
    const float* br    = (const float*)d_in[13];
    const float* gr    = (const float*)d_in[14];
    const float* brn   = (const float*)d_in[15];
    const int* src0 = ei;
    const int* dst0 = ei + E0;
    float* out = (float*)d_out;

    char* p = (char*)d_ws;
    auto alloc = [&](size_t bytes) -> void* {
        void* r = (void*)p;
        p += (bytes + 255) & ~(size_t)255;
        return r;
    };
    float* ew0  = (float*)alloc(E0 * 4);
    int* src1 = (int*)alloc(E1C * 4); int* dst1 = (int*)alloc(E1C * 4); float* ew1 = (float*)alloc(E1C * 4);
    int* src2 = (int*)alloc(E2C * 4); int* dst2 = (int*)alloc(E2C * 4); float* ew2 = (float*)alloc(E2C * 4);
    int* src3 = (int*)alloc(E3C * 4); int* dst3 = (int*)alloc(E3C * 4); float* ew3 = (float*)alloc(E3C * 4);
    float* hbuf = (float*)alloc((size_t)N0 * HD * 4);
    float* hW   = (float*)alloc((size_t)N0 * HD * 4);
    float* tmp  = (float*)alloc((size_t)N0 * HD * 4);
    float* xs0  = (float*)alloc((size_t)N0 * HD * 4);
    float* xs1  = (float*)alloc((size_t)KP1 * HD * 4);
    float* xs2  = (float*)alloc((size_t)KP2 * HD * 4);
    float* deg   = (float*)alloc(N0 * 4);
    float* dinv  = (float*)alloc(N0 * 4);
    float* score = (float*)alloc(N0 * 4);
    int*   pos1  = (int*)alloc(N0 * 4);
    int*   pos2  = (int*)alloc(N0 * 4);
    int*   pos3  = (int*)alloc(N0 * 4);
    float* vals  = (float*)alloc(KP1 * 4);
    int* perm1 = (int*)alloc(KP1 * 4);
    int* perm2 = (int*)alloc(KP2 * 4);
    int* perm3 = (int*)alloc(KP3 * 4);
    int* rowptr0 = (int*)alloc((N0 + 1) * 4);
    int* rowptr1 = (int*)alloc((KP1 + 1) * 4);
    int* rowptr2 = (int*)alloc((KP2 + 1) * 4);
    int* rowptr3 = (int*)alloc((KP3 + 1) * 4);
    int2* csrP0 = (int2*)alloc((size_t)E0 * 8);
    int2* csrP1 = (int2*)alloc((size_t)E1C * 8);
    int2* csrP2 = (int2*)alloc((size_t)E2C * 8);
    int2* csrP3 = (int2*)alloc((size_t)E3C * 8);
    int* cnt    = (int*)alloc(N0 * 4);
    int* cursor = (int*)alloc(N0 * 4);
    int* selws  = (int*)alloc((5120 + 64) * 4);   // hist0|hist1|hist2|dctr[3]
    int* hist0 = selws;
    int* hist1 = selws + 2048;
    int* hist2 = selws + 4096;
    unsigned* dctr = (unsigned*)(selws + 5120);
    int* bgt    = (int*)alloc(64 * 4);
    int* beq    = (int*)alloc(64 * 4);
    int* bsum   = (int*)alloc(64 * 4);
    int* bsumE  = (int*)alloc(1024 * 4);
    float2* partials = (float2*)alloc(((E0 + 255) / 256) * 8);
    float* cpart = (float*)alloc((size_t)CSB * HD * 4);
    float* mmv       = (float*)alloc(64);
    unsigned* dctrS  = (unsigned*)alloc(64);
    unsigned* prefix = (unsigned*)alloc(64);
    int* rem0        = (int*)alloc(64);
    int* rem1        = (int*)alloc(64);
    int* tiesN       = (int*)alloc(64);
    int* ecnt1       = (int*)alloc(64);
    int* ecnt2       = (int*)alloc(64);
    int* ecnt3       = (int*)alloc(64);

    const int EB = (E0 + 255) / 256;

    auto build_csr = [&](const int* esrc, const int* edst, const float* eww, int n,
                         int* rowptr, int2* csrP,
                         const int* EinPtr, int EinImm, int gridE) {
        int nb = (n + 1023) / 1024;
        k_sum_scan<<<nb, 256, 0, stream>>>(cnt, bsum, n, rowptr + n, dctrS);
        k_chunk_scan<<<nb, 256, 0, stream>>>(cnt, bsum, rowptr, cursor, n);
        k_csr_fill<<<gridE, 256, 0, stream>>>(esrc, edst, eww, cursor, csrP, EinPtr, EinImm);
    };

    auto run_gcn = [&](const float* hin, const int* rowptr, const int2* csrP,
                       const float* W, const float* bias, float fill, int n, int lrelu,
                       float* outbuf, const float* bn_g, const float* bn_b,
                       const float* up_h, const int* up_pos) {
        k_gemm128<<<(n + GT_ROWS - 1) / GT_ROWS, 256, 0, stream>>>(hin, W, hW, n, bn_g, bn_b, up_h, up_pos);
        k_deg_dinv<<<(n + 255) / 256, 256, 0, stream>>>(rowptr, csrP, fill, deg, dinv, n);
        k_gcn_gather<<<(n + 3) / 4, 256, 0, stream>>>(rowptr, csrP, deg, dinv, hW,
                                                      bias, fill, n, lrelu, outbuf);
    };

    auto run_pool = [&](const float* xin, int n, int k, const float* pvec,
                        const float* g, const float* b,
                        const int* esrc_in, const int* edst_in, const float* ew_in,
                        const int* EinPtr, int EinImm,
                        int* pos, int* perm,
                        int* esrc_out, int* edst_out, float* ew_out, int* ecntOut) {
        int nb = (n + 1023) / 1024;
        hipMemsetAsync(selws, 0, (5120 + 64) * 4, stream);
        k_score<<<(n + 3) / 4, 256, 0, stream>>>(xin, pvec, score, n);
        k_histpick<<<64, 256, 0, stream>>>(score, n, 0, prefix, hist0, k, (const int*)nullptr, rem0, dctr + 0);
        k_histpick<<<64, 256, 0, stream>>>(score, n, 1, prefix, hist1, 0, rem0, rem1, dctr + 1);
        k_histpick<<<64, 256, 0, stream>>>(score, n, 2, prefix, hist2, 0, rem1, tiesN, dctr + 2);
        k_cmp_count<<<nb, 256, 0, stream>>>(score, n, prefix, bgt, beq);
        k_scan_blocks2<<<1, 64, 0, stream>>>(bgt, beq, nb);
        k_cmp_assign<<<nb, 256, 0, stream>>>(score, n, k, prefix, tiesN, bgt, beq, pos, perm, vals);
        k_pool_bn<<<((size_t)k * HD + 255) / 256, 256, 0, stream>>>(xin, perm, vals, g, b, hbuf, k);
        hipMemsetAsync(cnt, 0, (size_t)k * 4, stream);
        k_ecompact_count<<<NBE, 256, 0, stream>>>(esrc_in, edst_in, ew_in, pos, EinPtr, EinImm, bsumE);
        k_scan1024<<<1, 1024, 0, stream>>>(bsumE, NBE, ecntOut);
        k_ecompact_assign<<<NBE, 256, 0, stream>>>(esrc_in, edst_in, ew_in, pos, EinPtr, EinImm,
                                                   bsumE, esrc_out, edst_out, ew_out, cnt);
    };

    // ---- init counters ----
    hipMemsetAsync((void*)dctrS, 0, 64, stream);
    hipMemsetAsync(cnt, 0, (size_t)N0 * 4, stream);

    // ---- edge weights + fused level-0 degree count ----
    k_edge_ew<<<EB, 256, 0, stream>>>(eattr, We_w, We_b, ew0, partials, E0);
    k_reduce_mm<<<1, 1024, 0, stream>>>(partials, EB, mmv);
    k_ew_norm_count<<<EB, 256, 0, stream>>>(ew0, mmv, dst0, cnt, E0);

    // ---- CSR level 0 ----
    build_csr(src0, dst0, ew0, N0, rowptr0, csrP0, (const int*)nullptr, E0, EB);

    // ---- level 0 (BN fused into GEMM A-staging) ----
    run_gcn(x, rowptr0, csrP0, Wdown, bdown, 1.0f, N0, 1, xs0, gnorm, bnorm, nullptr, nullptr);

    // ---- down: pool 1 / gcn 1 ----
    run_pool(xs0, N0, KP1, Wpool, gnorm + HD, bnorm + HD, src0, dst0, ew0,
             (const int*)nullptr, E0, pos1, perm1, src1, dst1, ew1, ecnt1);
    build_csr(src1, dst1, ew1, KP1, rowptr1, csrP1, ecnt1, 0, (E1C + 255) / 256);
    run_gcn(hbuf, rowptr1, csrP1, Wdown + 1 * HD * HD, bdown + 1 * HD, 1.0f, KP1, 1, xs1,
            nullptr, nullptr, nullptr, nullptr);

    // ---- down: pool 2 / gcn 2 ----
    run_pool(xs1, KP1, KP2, Wpool + HD, gnorm + 2 * HD, bnorm + 2 * HD, src1, dst1, ew1,
             ecnt1, 0, pos2, perm2, src2, dst2, ew2, ecnt2);
    build_csr(src2, dst2, ew2, KP2, rowptr2, csrP2, ecnt2, 0, (E2C + 255) / 256);
    run_gcn(hbuf, rowptr2, csrP2, Wdown + 2 * HD * HD, bdown + 2 * HD, 1.0f, KP2, 1, xs2,
            nullptr, nullptr, nullptr, nullptr);

    // ---- down: pool 3 / gcn 3 (no lrelu) ----
    run_pool(xs2, KP2, KP3, Wpool + 2 * HD, gnorm + 3 * HD, bnorm + 3 * HD, src2, dst2, ew2,
             ecnt2, 0, pos3, perm3, src3, dst3, ew3, ecnt3);
    build_csr(src3, dst3, ew3, KP3, rowptr3, csrP3, ecnt3, 0, (E3C + 255) / 256);
    run_gcn(hbuf, rowptr3, csrP3, Wdown + 3 * HD * HD, bdown + 3 * HD, 1.0f, KP3, 0, tmp,
            nullptr, nullptr, nullptr, nullptr);

    // ---- up 0: level 12500, CSR 2, fill=2 (unpool fused into GEMM) ----
    run_gcn(xs2, rowptr2, csrP2, Wup, bup, 2.0f, KP2, 1, tmp, nullptr, nullptr, tmp, pos3);

    // ---- up 1: level 25000, CSR 1 ----
    run_gcn(xs1, rowptr1, csrP1, Wup + 1 * HD * HD, bup + 1 * HD, 2.0f, KP1, 1, tmp,
            nullptr, nullptr, tmp, pos2);

    // ---- up 2: level 50000, CSR 0 (no lrelu) ----
    run_gcn(xs0, rowptr0, csrP0, Wup + 2 * HD * HD, bup + 2 * HD, 2.0f, N0, 0, tmp,
            nullptr, nullptr, tmp, pos1);

    // ---- readout (two-phase colsum + fused final) ----
    k_colsum_part<<<CSB, 256, 0, stream>>>(tmp, cpart, N0);
    k_colsum_final<<<1, 1024, 0, stream>>>(cpart, CSB, Wr, br, gr, brn, out);
}

// Round 10
// 875.959 us; speedup vs baseline: 2.2899x; 1.0663x over previous
//
#include <hip/hip_runtime.h>
#include <math.h>

// Problem constants (from reference)
#define N0   50000
#define E0   800000
#define HD   128          // D == H == 128
#define EHD  16
#define KP1  25000
#define KP2  12500
#define KP3  6250
#define BN_SCALE 0.9999950000374997f   // 1/sqrt(1+1e-5)
#define NEG_SLOPE 0.01f
// compacted-edge capacity per level (expected E/4^i, wide margin; inputs are fixed seed)
#define E1C  400000
#define E2C  120000
#define E3C  40000
#define NBE  782          // ceil(E0/1024)
#define CSB  782          // colsum phase-1 blocks

// ---------- helpers ----------
__device__ __forceinline__ unsigned fenc(float f) {
    unsigned u = __float_as_uint(f);
    return (u & 0x80000000u) ? ~u : (u | 0x80000000u);
}
// pack two fp32 -> bf16 pair (RNE), a in low 16, b in high 16
__device__ __forceinline__ unsigned packbf2(float a, float b) {
    unsigned ua = __float_as_uint(a);
    unsigned ub = __float_as_uint(b);
    ua = (ua + 0x7FFFu + ((ua >> 16) & 1u)) >> 16;
    ub = (ub + 0x7FFFu + ((ub >> 16) & 1u)) >> 16;
    return ua | (ub << 16);
}
// acc[0..7] += c * decode(h) ; h = 8 bf16 channels (exact expansion via <<16)
__device__ __forceinline__ void bf8_fma(float* acc, uint4 h, float c) {
    acc[0] += c * __uint_as_float(h.x << 16);
    acc[1] += c * __uint_as_float(h.x & 0xFFFF0000u);
    acc[2] += c * __uint_as_float(h.y << 16);
    acc[3] += c * __uint_as_float(h.y & 0xFFFF0000u);
    acc[4] += c * __uint_as_float(h.z << 16);
    acc[5] += c * __uint_as_float(h.z & 0xFFFF0000u);
    acc[6] += c * __uint_as_float(h.w << 16);
    acc[7] += c * __uint_as_float(h.w & 0xFFFF0000u);
}

// ---------- edge embedding: per-block partial min/max ----------
__global__ void k_edge_ew(const float* __restrict__ ea, const float* __restrict__ Ww,
                          const float* __restrict__ Wb, float* __restrict__ ew,
                          float2* __restrict__ partials, int E) {
    int e = blockIdx.x * 256 + threadIdx.x;
    float mn = 3.4e38f, mx = -3.4e38f;
    if (e < E) {
        const float4* a4 = (const float4*)(ea + (size_t)e * EHD);
        float s = Wb[0];
        #pragma unroll
        for (int q = 0; q < 4; ++q) {
            float4 a = a4[q];
            s += a.x * Ww[q*4+0] + a.y * Ww[q*4+1] + a.z * Ww[q*4+2] + a.w * Ww[q*4+3];
        }
        ew[e] = s;
        mn = s; mx = s;
    }
    #pragma unroll
    for (int off = 32; off > 0; off >>= 1) {
        mn = fminf(mn, __shfl_xor(mn, off));
        mx = fmaxf(mx, __shfl_xor(mx, off));
    }
    __shared__ float smn[4], smx[4];
    int lane = threadIdx.x & 63, wid = threadIdx.x >> 6;
    if (lane == 0) { smn[wid] = mn; smx[wid] = mx; }
    __syncthreads();
    if (threadIdx.x == 0) {
        float a = fminf(fminf(smn[0], smn[1]), fminf(smn[2], smn[3]));
        float b = fmaxf(fmaxf(smx[0], smx[1]), fmaxf(smx[2], smx[3]));
        partials[blockIdx.x] = make_float2(a, b);
    }
}

__global__ void __launch_bounds__(1024)
k_reduce_mm(const float2* __restrict__ partials, int nb, float* __restrict__ mmv) {
    float mn = 3.4e38f, mx = -3.4e38f;
    for (int i = threadIdx.x; i < nb; i += 1024) {
        float2 t = partials[i];
        mn = fminf(mn, t.x); mx = fmaxf(mx, t.y);
    }
    #pragma unroll
    for (int off = 32; off > 0; off >>= 1) {
        mn = fminf(mn, __shfl_xor(mn, off));
        mx = fmaxf(mx, __shfl_xor(mx, off));
    }
    __shared__ float smn[16], smx[16];
    int lane = threadIdx.x & 63, wid = threadIdx.x >> 6;
    if (lane == 0) { smn[wid] = mn; smx[wid] = mx; }
    __syncthreads();
    if (threadIdx.x == 0) {
        for (int w = 1; w < 16; ++w) { mn = fminf(mn, smn[w]); mx = fmaxf(mx, smx[w]); }
        mmv[0] = mn; mmv[1] = mx;
    }
}

// normalize + fused level-0 CSR degree count (cnt must be zeroed)
__global__ void k_ew_norm_count(float* __restrict__ ew, const float* __restrict__ mmv,
                                const int* __restrict__ dst, int* __restrict__ cnt, int E) {
    int e = blockIdx.x * 256 + threadIdx.x;
    if (e >= E) return;
    float mn = mmv[0];
    float sc = 1.0f / ((mmv[1] - mn) + 1e-7f);
    float w = (ew[e] - mn) * sc;
    ew[e] = w;
    if (w != 0.0f) atomicAdd(&cnt[dst[e]], 1);
}

// ---------- n x 128 @ 128 x 128 GEMM, fused optional BN / unpool-scatter on A;
// ---------- output written as bf16 (consumed only by the gather) ----------
#define GT_ROWS 64
__global__ void __launch_bounds__(256)
k_gemm128(const float* __restrict__ A, const float* __restrict__ W,
          unsigned* __restrict__ Cb, int n,
          const float* __restrict__ gs, const float* __restrict__ gb,
          const float* __restrict__ up_h, const int* __restrict__ up_pos) {
    __shared__ float As[GT_ROWS][132];   // +4 pad
    int tid = threadIdx.x;               // 256
    int row0 = blockIdx.x * GT_ROWS;
    int maxr = n - row0;
    {
        #pragma unroll
        for (int it = 0; it < 8; ++it) {
            int idx = it * 256 + tid;
            int r = idx >> 5, q = idx & 31;
            float4 v = make_float4(0.f, 0.f, 0.f, 0.f);
            if (r < maxr) {
                v = ((const float4*)(A + (size_t)(row0 + r) * HD))[q];
                if (up_pos) {
                    int sl = up_pos[row0 + r];
                    if (sl >= 0) {
                        float4 u = ((const float4*)(up_h + (size_t)sl * HD))[q];
                        v.x += u.x; v.y += u.y; v.z += u.z; v.w += u.w;
                    }
                }
                if (gs) {
                    float4 g4 = ((const float4*)gs)[q];
                    float4 b4 = ((const float4*)gb)[q];
                    v.x = v.x * (g4.x * BN_SCALE) + b4.x;
                    v.y = v.y * (g4.y * BN_SCALE) + b4.y;
                    v.z = v.z * (g4.z * BN_SCALE) + b4.z;
                    v.w = v.w * (g4.w * BN_SCALE) + b4.w;
                }
            }
            *(float4*)&As[r][q * 4] = v;
        }
    }
    __syncthreads();
    int cg = tid & 31;
    int rg = tid >> 5;
    float4 acc[8];
    #pragma unroll
    for (int j = 0; j < 8; ++j) acc[j] = make_float4(0.f, 0.f, 0.f, 0.f);
    const float4* W4 = (const float4*)W;
    #pragma unroll 4
    for (int k = 0; k < HD; k += 4) {
        float4 w0 = W4[(k + 0) * 32 + cg];
        float4 w1 = W4[(k + 1) * 32 + cg];
        float4 w2 = W4[(k + 2) * 32 + cg];
        float4 w3 = W4[(k + 3) * 32 + cg];
        #pragma unroll
        for (int jj = 0; jj < 4; ++jj) {
            float4 a = *(const float4*)&As[4 * rg + jj][k];
            acc[jj].x += a.x * w0.x + a.y * w1.x + a.z * w2.x + a.w * w3.x;
            acc[jj].y += a.x * w0.y + a.y * w1.y + a.z * w2.y + a.w * w3.y;
            acc[jj].z += a.x * w0.z + a.y * w1.z + a.z * w2.z + a.w * w3.z;
            acc[jj].w += a.x * w0.w + a.y * w1.w + a.z * w2.w + a.w * w3.w;
        }
        #pragma unroll
        for (int jj = 0; jj < 4; ++jj) {
            float4 a = *(const float4*)&As[32 + 4 * rg + jj][k];
            acc[4 + jj].x += a.x * w0.x + a.y * w1.x + a.z * w2.x + a.w * w3.x;
            acc[4 + jj].y += a.x * w0.y + a.y * w1.y + a.z * w2.y + a.w * w3.y;
            acc[4 + jj].z += a.x * w0.z + a.y * w1.z + a.z * w2.z + a.w * w3.z;
            acc[4 + jj].w += a.x * w0.w + a.y * w1.w + a.z * w2.w + a.w * w3.w;
        }
    }
    #pragma unroll
    for (int jj = 0; jj < 4; ++jj) {
        int r = 4 * rg + jj;
        if (r < maxr) {
            uint2 pk = make_uint2(packbf2(acc[jj].x, acc[jj].y), packbf2(acc[jj].z, acc[jj].w));
            ((uint2*)(Cb + (size_t)(row0 + r) * 64))[cg] = pk;
        }
    }
    #pragma unroll
    for (int jj = 0; jj < 4; ++jj) {
        int r = 32 + 4 * rg + jj;
        if (r < maxr) {
            uint2 pk = make_uint2(packbf2(acc[4+jj].x, acc[4+jj].y), packbf2(acc[4+jj].z, acc[4+jj].w));
            ((uint2*)(Cb + (size_t)(row0 + r) * 64))[cg] = pk;
        }
    }
}

// ---------- CSR build: fused chunk-sum + block-scan (done-counter, self-resetting) ----------
__global__ void k_sum_scan(const int* __restrict__ cnt, int* __restrict__ bsum, int n,
                           int* __restrict__ totalOut, unsigned* __restrict__ dctr) {
    int base = blockIdx.x * 1024;
    int s = 0;
    #pragma unroll
    for (int it = 0; it < 4; ++it) {
        int i = base + it * 256 + threadIdx.x;
        if (i < n) s += cnt[i];
    }
    __shared__ int ws[4];
    __shared__ int lastFlag;
    int lane = threadIdx.x & 63, wid = threadIdx.x >> 6;
    #pragma unroll
    for (int off = 32; off > 0; off >>= 1) s += __shfl_down(s, off);
    if (lane == 0) ws[wid] = s;
    __syncthreads();
    if (threadIdx.x == 0) {
        __hip_atomic_store(&bsum[blockIdx.x], ws[0] + ws[1] + ws[2] + ws[3],
                           __ATOMIC_RELAXED, __HIP_MEMORY_SCOPE_AGENT);
        unsigned prev = __hip_atomic_fetch_add(dctr, 1u, __ATOMIC_ACQ_REL, __HIP_MEMORY_SCOPE_AGENT);
        lastFlag = (prev == gridDim.x - 1);
    }
    __syncthreads();
    if (!lastFlag) return;
    if (threadIdx.x < 64) {
        int nb = gridDim.x;
        int t = threadIdx.x;
        int v = (t < nb) ? __hip_atomic_load(&bsum[t], __ATOMIC_RELAXED, __HIP_MEMORY_SCOPE_AGENT) : 0;
        int x = v;
        #pragma unroll
        for (int off = 1; off < 64; off <<= 1) {
            int y = __shfl_up(x, off);
            if (t >= off) x += y;
        }
        if (t < nb) bsum[t] = x - v;
        if (t == nb - 1) totalOut[0] = x;
    }
    if (threadIdx.x == 0)
        __hip_atomic_store(dctr, 0u, __ATOMIC_RELAXED, __HIP_MEMORY_SCOPE_AGENT);
}

__global__ void k_chunk_scan(const int* __restrict__ cnt, const int* __restrict__ bo,
                             int* __restrict__ rowptr, int* __restrict__ cursor, int n) {
    __shared__ int wsum[4];
    __shared__ int running;
    int base = blockIdx.x * 1024;
    if (threadIdx.x == 0) running = bo[blockIdx.x];
    __syncthreads();
    int lane = threadIdx.x & 63, wid = threadIdx.x >> 6;
    #pragma unroll
    for (int it = 0; it < 4; ++it) {
        int i = base + it * 256 + threadIdx.x;
        int v = (i < n) ? cnt[i] : 0;
        int x = v;
        #pragma unroll
        for (int off = 1; off < 64; off <<= 1) {
            int y = __shfl_up(x, off);
            if (lane >= off) x += y;
        }
        if (lane == 63) wsum[wid] = x;
        __syncthreads();
        int wb = 0;
        for (int w = 0; w < wid; ++w) wb += wsum[w];
        int excl = running + wb + x - v;
        if (i < n) { rowptr[i] = excl; cursor[i] = excl; }
        __syncthreads();
        if (threadIdx.x == 0) running += wsum[0] + wsum[1] + wsum[2] + wsum[3];
        __syncthreads();
    }
}

// packed CSR entry: {src, float_bits(w)} — one 8B store per edge
__global__ void k_csr_fill(const int* __restrict__ src, const int* __restrict__ dst,
                           const float* __restrict__ w, int* __restrict__ cursor,
                           int2* __restrict__ csr,
                           const int* __restrict__ EinPtr, int EinImm) {
    int Ein = EinPtr ? EinPtr[0] : EinImm;
    int e = blockIdx.x * 256 + threadIdx.x;
    if (e >= Ein) return;
    float wv = w[e];
    if (wv == 0.0f) return;
    int slot = atomicAdd(&cursor[dst[e]], 1);
    csr[slot] = make_int2(src[e], __float_as_int(wv));
}

// ---------- degree from CSR ----------
__global__ void k_deg_dinv(const int* __restrict__ rowptr, const int2* __restrict__ csr,
                           float fill, float* __restrict__ deg, float* __restrict__ dinv, int n) {
    int v = blockIdx.x * 256 + threadIdx.x;
    if (v >= n) return;
    float s = fill;
    int rs = rowptr[v], re = rowptr[v + 1];
    for (int j = rs; j < re; ++j) s += __int_as_float(csr[j].y);
    deg[v] = s;
    dinv[v] = rsqrtf(s);
}

// ---------- fused GCN gather: bf16 rows, 4 neighbors/wave, 16 lanes x 16B each ----------
__global__ void __launch_bounds__(256)
k_gcn_gather(const int* __restrict__ rowptr, const int2* __restrict__ csr,
             const float* __restrict__ deg, const float* __restrict__ dinv,
             const unsigned* __restrict__ hWb,   // bf16 rows: 64 uints per row
             const float* __restrict__ bias,
             float fill, int n, int lrelu, float* __restrict__ out) {
    int v = blockIdx.x * 4 + (threadIdx.x >> 6);
    int lane = threadIdx.x & 63;
    if (v >= n) return;
    int rs = rowptr[v], re = rowptr[v + 1];
    float dv = dinv[v];
    int quarter = lane >> 4;   // neighbor slot within group of 4
    int qi = lane & 15;        // 16B chunk within 256B row (8 channels)
    float acc[8];
    #pragma unroll
    for (int i = 0; i < 8; ++i) acc[i] = 0.f;
    for (int base = rs; base < re; base += 64) {
        int idx = base + lane;
        int s_r = 0; float c_r = 0.f;
        if (idx < re) {
            int2 ent = csr[idx];
            s_r = ent.x;
            c_r = dinv[s_r] * __int_as_float(ent.y) * dv;
        }
        int cnt = min(64, re - base);
        int groups = cnt >> 2;
        int t = 0;
        for (; t + 1 < groups; t += 2) {
            int j0 = 4 * t + quarter, j1 = j0 + 4;
            int   s0 = __shfl(s_r, j0); float c0 = __shfl(c_r, j0);
            int   s1 = __shfl(s_r, j1); float c1 = __shfl(c_r, j1);
            uint4 h0 = ((const uint4*)(hWb + (size_t)s0 * 64))[qi];
            uint4 h1 = ((const uint4*)(hWb + (size_t)s1 * 64))[qi];
            bf8_fma(acc, h0, c0);
            bf8_fma(acc, h1, c1);
        }
        for (; t < groups; ++t) {
            int j = 4 * t + quarter;
            int s = __shfl(s_r, j); float c = __shfl(c_r, j);
            uint4 h = ((const uint4*)(hWb + (size_t)s * 64))[qi];
            bf8_fma(acc, h, c);
        }
        int rem = cnt & 3;
        if (quarter < rem) {
            int j = groups * 4 + quarter;
            int s = __shfl(s_r, j); float c = __shfl(c_r, j);
            uint4 h = ((const uint4*)(hWb + (size_t)s * 64))[qi];
            bf8_fma(acc, h, c);
        }
    }
    #pragma unroll
    for (int i = 0; i < 8; ++i) {
        acc[i] += __shfl_xor(acc[i], 16);
        acc[i] += __shfl_xor(acc[i], 32);
    }
    if (quarter == 0) {
        uint4 hs = ((const uint4*)(hWb + (size_t)v * 64))[qi];
        float sc = fill / deg[v];
        float hv[8];
        hv[0] = __uint_as_float(hs.x << 16); hv[1] = __uint_as_float(hs.x & 0xFFFF0000u);
        hv[2] = __uint_as_float(hs.y << 16); hv[3] = __uint_as_float(hs.y & 0xFFFF0000u);
        hv[4] = __uint_as_float(hs.z << 16); hv[5] = __uint_as_float(hs.z & 0xFFFF0000u);
        hv[6] = __uint_as_float(hs.w << 16); hv[7] = __uint_as_float(hs.w & 0xFFFF0000u);
        float4 b0 = ((const float4*)bias)[2 * qi];
        float4 b1 = ((const float4*)bias)[2 * qi + 1];
        float o[8];
        o[0] = acc[0] + sc * hv[0] + b0.x;
        o[1] = acc[1] + sc * hv[1] + b0.y;
        o[2] = acc[2] + sc * hv[2] + b0.z;
        o[3] = acc[3] + sc * hv[3] + b0.w;
        o[4] = acc[4] + sc * hv[4] + b1.x;
        o[5] = acc[5] + sc * hv[5] + b1.y;
        o[6] = acc[6] + sc * hv[6] + b1.z;
        o[7] = acc[7] + sc * hv[7] + b1.w;
        if (lrelu) {
            #pragma unroll
            for (int i = 0; i < 8; ++i) o[i] = (o[i] > 0.f) ? o[i] : NEG_SLOPE * o[i];
        }
        float4* orow = (float4*)(out + (size_t)v * HD);
        orow[2 * qi]     = make_float4(o[0], o[1], o[2], o[3]);
        orow[2 * qi + 1] = make_float4(o[4], o[5], o[6], o[7]);
    }
}

// ---------- TopK pooling ----------
// score + fold-in zeroing of the selection workspace (hist bins; 5120 ints)
__global__ void k_score(const float* __restrict__ x, const float* __restrict__ p,
                        float* __restrict__ score, int n, int* __restrict__ selws) {
    for (int i = blockIdx.x * 256 + threadIdx.x; i < 5120; i += gridDim.x * 256) selws[i] = 0;
    int lane = threadIdx.x & 63;
    float pv0 = p[lane], pv1 = p[lane + 64];
    float ps = pv0 * pv0 + pv1 * pv1;
    #pragma unroll
    for (int off = 32; off > 0; off >>= 1) ps += __shfl_xor(ps, off);
    float rnorm = 1.0f / sqrtf(ps);
    int node = blockIdx.x * 4 + (threadIdx.x >> 6);
    if (node >= n) return;
    const float* row = x + (size_t)node * HD;
    float s = row[lane] * pv0 + row[lane + 64] * pv1;
    #pragma unroll
    for (int off = 32; off > 0; off >>= 1) s += __shfl_xor(s, off);
    if (lane == 0) score[node] = tanhf(s * rnorm);
}

// fused hist pass + last-block pick (done-counter, self-resetting)
__global__ void __launch_bounds__(256)
k_histpick(const float* __restrict__ score, int n, int pass,
           unsigned* __restrict__ prefix, int* __restrict__ hist,
           int kImm, const int* __restrict__ remIn, int* __restrict__ remOut,
           unsigned* __restrict__ doneCtr) {
    __shared__ int lh[2048];
    int nbins = (pass == 2) ? 1024 : 2048;
    for (int i = threadIdx.x; i < nbins; i += 256) lh[i] = 0;
    __syncthreads();
    unsigned pfx = (pass != 0) ? prefix[0] : 0u;
    int stride = gridDim.x * 256;
    for (int i = blockIdx.x * 256 + threadIdx.x; i < n; i += stride) {
        unsigned u = fenc(score[i]);
        int bin; bool ok;
        if (pass == 0)      { bin = u >> 21;            ok = true; }
        else if (pass == 1) { bin = (u >> 10) & 2047;   ok = ((u >> 21) == (pfx >> 21)); }
        else                { bin = u & 1023;           ok = ((u >> 10) == (pfx >> 10)); }
        if (ok) atomicAdd(&lh[bin], 1);
    }
    __syncthreads();
    for (int i = threadIdx.x; i < nbins; i += 256) {
        int c = lh[i];
        if (c) __hip_atomic_fetch_add(&hist[i], c, __ATOMIC_RELAXED, __HIP_MEMORY_SCOPE_AGENT);
    }
    __syncthreads();
    __shared__ int lastFlag;
    if (threadIdx.x == 0) {
        unsigned prev = __hip_atomic_fetch_add(doneCtr, 1u, __ATOMIC_ACQ_REL, __HIP_MEMORY_SCOPE_AGENT);
        lastFlag = (prev == gridDim.x - 1);
    }
    __syncthreads();
    if (!lastFlag) return;
    __shared__ int wsum[4];
    int k = remIn ? remIn[0] : kImm;
    int t = threadIdx.x;
    int per = nbins >> 8;
    int hi = nbins - t * per, lo = hi - per;
    int s = 0;
    for (int b = lo; b < hi; ++b)
        s += __hip_atomic_load(&hist[b], __ATOMIC_RELAXED, __HIP_MEMORY_SCOPE_AGENT);
    int lane = t & 63, wid = t >> 6;
    int x = s;
    #pragma unroll
    for (int off = 1; off < 64; off <<= 1) {
        int y = __shfl_up(x, off);
        if (lane >= off) x += y;
    }
    if (lane == 63) wsum[wid] = x;
    __syncthreads();
    int wb = 0;
    for (int w = 0; w < wid; ++w) wb += wsum[w];
    int excl = wb + x - s;
    if (k > excl && k <= excl + s) {
        int cum = excl;
        int shift = (pass == 0) ? 21 : (pass == 1) ? 10 : 0;
        for (int b = hi - 1; b >= lo; --b) {
            int h = __hip_atomic_load(&hist[b], __ATOMIC_RELAXED, __HIP_MEMORY_SCOPE_AGENT);
            if (k <= cum + h) {
                unsigned base = (pass == 0) ? 0u : prefix[0];
                prefix[0] = base | ((unsigned)b << shift);
                remOut[0] = k - cum;
                break;
            }
            cum += h;
        }
    }
    __syncthreads();
    if (threadIdx.x == 0)
        __hip_atomic_store(doneCtr, 0u, __ATOMIC_RELAXED, __HIP_MEMORY_SCOPE_AGENT);
}

// ---------- compaction count + fused dual scan (done-counter, self-resetting) ----------
__global__ void k_cmp_countscan(const float* __restrict__ score, int n,
                                const unsigned* __restrict__ prefix,
                                int* __restrict__ bgt, int* __restrict__ beq,
                                unsigned* __restrict__ dctr) {
    unsigned T = prefix[0];
    int base = blockIdx.x * 1024;
    int gt = 0, eq = 0;
    #pragma unroll
    for (int it = 0; it < 4; ++it) {
        int i = base + it * 256 + threadIdx.x;
        if (i < n) {
            unsigned u = fenc(score[i]);
            gt += (u > T); eq += (u == T);
        }
    }
    __shared__ int sg[4], se[4];
    __shared__ int lastFlag;
    int lane = threadIdx.x & 63, wid = threadIdx.x >> 6;
    #pragma unroll
    for (int off = 32; off > 0; off >>= 1) { gt += __shfl_down(gt, off); eq += __shfl_down(eq, off); }
    if (lane == 0) { sg[wid] = gt; se[wid] = eq; }
    __syncthreads();
    if (threadIdx.x == 0) {
        __hip_atomic_store(&bgt[blockIdx.x], sg[0] + sg[1] + sg[2] + sg[3],
                           __ATOMIC_RELAXED, __HIP_MEMORY_SCOPE_AGENT);
        __hip_atomic_store(&beq[blockIdx.x], se[0] + se[1] + se[2] + se[3],
                           __ATOMIC_RELAXED, __HIP_MEMORY_SCOPE_AGENT);
        unsigned prev = __hip_atomic_fetch_add(dctr, 1u, __ATOMIC_ACQ_REL, __HIP_MEMORY_SCOPE_AGENT);
        lastFlag = (prev == gridDim.x - 1);
    }
    __syncthreads();
    if (!lastFlag) return;
    if (threadIdx.x < 64) {
        int nb = gridDim.x;
        int t = threadIdx.x;
        int va = (t < nb) ? __hip_atomic_load(&bgt[t], __ATOMIC_RELAXED, __HIP_MEMORY_SCOPE_AGENT) : 0;
        int vb = (t < nb) ? __hip_atomic_load(&beq[t], __ATOMIC_RELAXED, __HIP_MEMORY_SCOPE_AGENT) : 0;
        int xa = va, xb = vb;
        #pragma unroll
        for (int off = 1; off < 64; off <<= 1) {
            int ya = __shfl_up(xa, off), yb = __shfl_up(xb, off);
            if (t >= off) { xa += ya; xb += yb; }
        }
        if (t < nb) { bgt[t] = xa - va; beq[t] = xb - vb; }
    }
    if (threadIdx.x == 0)
        __hip_atomic_store(dctr, 0u, __ATOMIC_RELAXED, __HIP_MEMORY_SCOPE_AGENT);
}

__global__ void k_cmp_assign(const float* __restrict__ score, int n, int kcap,
                             const unsigned* __restrict__ prefix,
                             const int* __restrict__ selTies,
                             const int* __restrict__ bgt, const int* __restrict__ beq,
                             int* __restrict__ pos, int* __restrict__ perm,
                             float* __restrict__ vals) {
    unsigned T = prefix[0];
    int tiesNeed = selTies[0];
    __shared__ int wgt[4], weq[4];
    __shared__ int rgt, req;
    int base = blockIdx.x * 1024;
    if (threadIdx.x == 0) { rgt = bgt[blockIdx.x]; req = beq[blockIdx.x]; }
    __syncthreads();
    int lane = threadIdx.x & 63, wid = threadIdx.x >> 6;
    #pragma unroll
    for (int it = 0; it < 4; ++it) {
        int i = base + it * 256 + threadIdx.x;
        bool in = i < n;
        float sc = in ? score[i] : 0.f;
        unsigned u = in ? fenc(sc) : 0u;
        bool g = in && (u > T);
        bool e = in && (u == T);
        unsigned long long mg = __ballot(g), me = __ballot(e);
        int lgt = __popcll(mg & ((1ull << lane) - 1ull));
        int leq = __popcll(me & ((1ull << lane) - 1ull));
        if (lane == 0) { wgt[wid] = __popcll(mg); weq[wid] = __popcll(me); }
        __syncthreads();
        int wbg = 0, wbe = 0;
        for (int w = 0; w < wid; ++w) { wbg += wgt[w]; wbe += weq[w]; }
        int gtRank = rgt + wbg + lgt;
        int tieRank = req + wbe + leq;
        if (in) {
            int slot = -1;
            if (g) slot = gtRank + min(tieRank, tiesNeed);
            else if (e && tieRank < tiesNeed) slot = gtRank + tieRank;
            if (slot >= kcap) slot = -1;
            pos[i] = slot;
            if (slot >= 0) { perm[slot] = i; vals[slot] = sc; }
        }
        __syncthreads();
        if (threadIdx.x == 0) {
            rgt += wgt[0] + wgt[1] + wgt[2] + wgt[3];
            req += weq[0] + weq[1] + weq[2] + weq[3];
        }
        __syncthreads();
    }
}

// xp = x[perm] * vals, then BN  (fused)
__global__ void k_pool_bn(const float* __restrict__ x, const int* __restrict__ perm,
                          const float* __restrict__ vals, const float* __restrict__ g,
                          const float* __restrict__ b, float* __restrict__ out, int k) {
    int idx = blockIdx.x * 256 + threadIdx.x;
    if (idx >= k * HD) return;
    int slot = idx >> 7, c = idx & 127;
    int v = perm[slot];
    out[idx] = (x[(size_t)v * HD + c] * vals[slot]) * (g[c] * BN_SCALE) + b[c];
}

// ---------- edge compaction: zero-cnt + count + fused scan (done-counter) ----------
__global__ void k_ecompact_countscan(const int* __restrict__ src, const int* __restrict__ dst,
                                     const float* __restrict__ w, const int* __restrict__ pos,
                                     const int* __restrict__ EinPtr, int EinImm, int kNodes,
                                     int* __restrict__ bsumE, int* __restrict__ ecntOut,
                                     int* __restrict__ cnt, unsigned* __restrict__ dctr) {
    int Ein = EinPtr ? EinPtr[0] : EinImm;
    // zero next-level degree counters (consumed by the assign kernel after this one)
    for (int i = blockIdx.x * 256 + threadIdx.x; i < kNodes; i += gridDim.x * 256) cnt[i] = 0;
    int base = blockIdx.x * 1024;
    int c = 0;
    #pragma unroll
    for (int it = 0; it < 4; ++it) {
        int e = base + it * 256 + threadIdx.x;
        if (e < Ein) {
            float wv = w[e];
            if (wv != 0.0f && pos[src[e]] >= 0 && pos[dst[e]] >= 0) ++c;
        }
    }
    __shared__ int ws[4];
    __shared__ int lastFlag;
    int lane = threadIdx.x & 63, wid = threadIdx.x >> 6;
    #pragma unroll
    for (int off = 32; off > 0; off >>= 1) c += __shfl_down(c, off);
    if (lane == 0) ws[wid] = c;
    __syncthreads();
    if (threadIdx.x == 0) {
        __hip_atomic_store(&bsumE[blockIdx.x], ws[0] + ws[1] + ws[2] + ws[3],
                           __ATOMIC_RELAXED, __HIP_MEMORY_SCOPE_AGENT);
        unsigned prev = __hip_atomic_fetch_add(dctr, 1u, __ATOMIC_ACQ_REL, __HIP_MEMORY_SCOPE_AGENT);
        lastFlag = (prev == gridDim.x - 1);
    }
    __syncthreads();
    if (!lastFlag) return;
    // last block: exclusive scan of bsumE[0..nb), nb <= 1024, 4 entries/thread
    {
        __shared__ int wtot[4];
        int nb = gridDim.x;
        int t = threadIdx.x;
        int i0 = t * 4;
        int v0 = (i0 + 0 < nb) ? __hip_atomic_load(&bsumE[i0 + 0], __ATOMIC_RELAXED, __HIP_MEMORY_SCOPE_AGENT) : 0;
        int v1 = (i0 + 1 < nb) ? __hip_atomic_load(&bsumE[i0 + 1], __ATOMIC_RELAXED, __HIP_MEMORY_SCOPE_AGENT) : 0;
        int v2 = (i0 + 2 < nb) ? __hip_atomic_load(&bsumE[i0 + 2], __ATOMIC_RELAXED, __HIP_MEMORY_SCOPE_AGENT) : 0;
        int v3 = (i0 + 3 < nb) ? __hip_atomic_load(&bsumE[i0 + 3], __ATOMIC_RELAXED, __HIP_MEMORY_SCOPE_AGENT) : 0;
        int tot = v0 + v1 + v2 + v3;
        int x2 = tot;
        #pragma unroll
        for (int off = 1; off < 64; off <<= 1) {
            int y = __shfl_up(x2, off);
            if (lane >= off) x2 += y;
        }
        if (lane == 63) wtot[wid] = x2;
        __syncthreads();
        int wb = 0;
        for (int q = 0; q < wid; ++q) wb += wtot[q];
        int excl = wb + x2 - tot;
        if (i0 + 0 < nb) bsumE[i0 + 0] = excl;
        if (i0 + 1 < nb) bsumE[i0 + 1] = excl + v0;
        if (i0 + 2 < nb) bsumE[i0 + 2] = excl + v0 + v1;
        if (i0 + 3 < nb) bsumE[i0 + 3] = excl + v0 + v1 + v2;
        if (t == 255) ecntOut[0] = wtot[0] + wtot[1] + wtot[2] + wtot[3];
    }
    __syncthreads();
    if (threadIdx.x == 0)
        __hip_atomic_store(dctr, 0u, __ATOMIC_RELAXED, __HIP_MEMORY_SCOPE_AGENT);
}

__global__ void k_ecompact_assign(const int* __restrict__ src, const int* __restrict__ dst,
                                  const float* __restrict__ w, const int* __restrict__ pos,
                                  const int* __restrict__ EinPtr, int EinImm,
                                  const int* __restrict__ bsumE,
                                  int* __restrict__ nsrc, int* __restrict__ ndst,
                                  float* __restrict__ nw, int* __restrict__ cnt) {
    int Ein = EinPtr ? EinPtr[0] : EinImm;
    __shared__ int wcnt[4];
    __shared__ int running;
    if (threadIdx.x == 0) running = bsumE[blockIdx.x];
    __syncthreads();
    int base = blockIdx.x * 1024;
    int lane = threadIdx.x & 63, wid = threadIdx.x >> 6;
    #pragma unroll
    for (int it = 0; it < 4; ++it) {
        int e = base + it * 256 + threadIdx.x;
        bool valid = false; int ns = 0, nd = 0; float wv = 0.f;
        if (e < Ein) {
            wv = w[e];
            if (wv != 0.0f) {
                ns = pos[src[e]]; nd = pos[dst[e]];
                valid = (ns >= 0) && (nd >= 0);
            }
        }
        unsigned long long m = __ballot(valid);
        int r = __popcll(m & ((1ull << lane) - 1ull));
        if (lane == 0) wcnt[wid] = __popcll(m);
        __syncthreads();
        int wb = 0;
        for (int w2 = 0; w2 < wid; ++w2) wb += wcnt[w2];
        if (valid) {
            int slot = running + wb + r;
            nsrc[slot] = ns; ndst[slot] = nd; nw[slot] = wv;
            atomicAdd(&cnt[nd], 1);
        }
        __syncthreads();
        if (threadIdx.x == 0) running += wcnt[0] + wcnt[1] + wcnt[2] + wcnt[3];
        __syncthreads();
    }
}

// ---------- readout: two-phase column sum + fused final matvec/BN ----------
__global__ void __launch_bounds__(256)
k_colsum_part(const float* __restrict__ h, float* __restrict__ cpart, int n) {
    int c = threadIdx.x & 127;
    int rh = threadIdx.x >> 7;
    int r0 = blockIdx.x * 64;
    int r1 = min(n, r0 + 64);
    float local = 0.f;
    for (int r = r0 + rh; r < r1; r += 2) local += h[(size_t)r * HD + c];
    __shared__ float sh[256];
    sh[threadIdx.x] = local;
    __syncthreads();
    if (threadIdx.x < 128) cpart[(size_t)blockIdx.x * HD + c] = sh[c] + sh[c + 128];
}

__global__ void __launch_bounds__(1024)
k_colsum_final(const float* __restrict__ cpart, int nb,
               const float* __restrict__ Wr, const float* __restrict__ br,
               const float* __restrict__ gr, const float* __restrict__ brn,
               float* __restrict__ out) {
    __shared__ float gsh[HD];
    int c = threadIdx.x & 127;
    int seg = threadIdx.x >> 7;
    float local = 0.f;
    for (int b = seg; b < nb; b += 8) local += cpart[(size_t)b * HD + c];
    __shared__ float sh[1024];
    sh[threadIdx.x] = local;
    __syncthreads();
    if (threadIdx.x < 128) {
        float s = 0.f;
        #pragma unroll
        for (int q = 0; q < 8; ++q) s += sh[c + q * 128];
        gsh[c] = s;
    }
    __syncthreads();
    if (threadIdx.x < 128) {
        float s = br[c];
        for (int k = 0; k < HD; ++k) s += gsh[k] * Wr[k * HD + c];
        out[c] = s * (gr[c] * BN_SCALE) + brn[c];
    }
}

// ---------- orchestration ----------
extern "C" void kernel_launch(void* const* d_in, const int* in_sizes, int n_in,
                              void* d_out, int out_size, void* d_ws, size_t ws_size,
                              hipStream_t stream) {
    const float* x     = (const float*)d_in[0];
    const int*   ei    = (const int*)d_in[1];
    const float* eattr = (const float*)d_in[2];
    const float* We_w  = (const float*)d_in[3];
    const float* We_b  = (const float*)d_in[4];
    const float* Wdown = (const float*)d_in[5];
    const float* bdown = (const float*)d_in[6];
    const float* Wpool = (const float*)d_in[7];
    const float* Wup   = (const float*)d_in[8];
    const float* bup   = (const float*)d_in[9];
    const float* gnorm = (const float*)d_in[10];
    const float* bnorm = (const float*)d_in[11];
    const float* Wr    = (const float*)d_in[12];
    const float* br    = (const float*)d_in[13];
    const float* gr    = (const float*)d_in[14];
    const float* brn   = (const float*)d_in[15];
    const int* src0 = ei;
    const int* dst0 = ei + E0;
    float* out = (float*)d_out;

    char* p = (char*)d_ws;
    auto alloc = [&](size_t bytes) -> void* {
        void* r = (void*)p;
        p += (bytes + 255) & ~(size_t)255;
        return r;
    };
    float* ew0  = (float*)alloc(E0 * 4);
    int* src1 = (int*)alloc(E1C * 4); int* dst1 = (int*)alloc(E1C * 4); float* ew1 = (float*)alloc(E1C * 4);
    int* src2 = (int*)alloc(E2C * 4); int* dst2 = (int*)alloc(E2C * 4); float* ew2 = (float*)alloc(E2C * 4);
    int* src3 = (int*)alloc(E3C * 4); int* dst3 = (int*)alloc(E3C * 4); float* ew3 = (float*)alloc(E3C * 4);
    float* hbuf = (float*)alloc((size_t)N0 * HD * 4);
    unsigned* hWb = (unsigned*)alloc((size_t)N0 * 64 * 4);   // bf16 GEMM output (256B/row)
    float* tmp  = (float*)alloc((size_t)N0 * HD * 4);
    float* xs0  = (float*)alloc((size_t)N0 * HD * 4);
    float* xs1  = (float*)alloc((size_t)KP1 * HD * 4);
    float* xs2  = (float*)alloc((size_t)KP2 * HD * 4);
    float* deg   = (float*)alloc(N0 * 4);
    float* dinv  = (float*)alloc(N0 * 4);
    float* score = (float*)alloc(N0 * 4);
    int*   pos1  = (int*)alloc(N0 * 4);
    int*   pos2  = (int*)alloc(N0 * 4);
    int*   pos3  = (int*)alloc(N0 * 4);
    float* vals  = (float*)alloc(KP1 * 4);
    int* perm1 = (int*)alloc(KP1 * 4);
    int* perm2 = (int*)alloc(KP2 * 4);
    int* perm3 = (int*)alloc(KP3 * 4);
    int* rowptr0 = (int*)alloc((N0 + 1) * 4);
    int* rowptr1 = (int*)alloc((KP1 + 1) * 4);
    int* rowptr2 = (int*)alloc((KP2 + 1) * 4);
    int* rowptr3 = (int*)alloc((KP3 + 1) * 4);
    int2* csrP0 = (int2*)alloc((size_t)E0 * 8);
    int2* csrP1 = (int2*)alloc((size_t)E1C * 8);
    int2* csrP2 = (int2*)alloc((size_t)E2C * 8);
    int2* csrP3 = (int2*)alloc((size_t)E3C * 8);
    int* cnt    = (int*)alloc(N0 * 4);
    int* cursor = (int*)alloc(N0 * 4);
    int* selws  = (int*)alloc(5120 * 4);     // hist0|hist1|hist2 (zeroed by k_score)
    int* hist0 = selws;
    int* hist1 = selws + 2048;
    int* hist2 = selws + 4096;
    int* bgt    = (int*)alloc(64 * 4);
    int* beq    = (int*)alloc(64 * 4);
    int* bsum   = (int*)alloc(64 * 4);
    int* bsumE  = (int*)alloc(1024 * 4);
    float2* partials = (float2*)alloc(((E0 + 255) / 256) * 8);
    float* cpart = (float*)alloc((size_t)CSB * HD * 4);
    float* mmv       = (float*)alloc(64);
    unsigned* ctrws  = (unsigned*)alloc(64 * 4);   // all done-counters (self-resetting; zeroed once)
    unsigned* dctrS  = ctrws + 0;    // csr-build sum_scan
    unsigned* dctrH  = ctrws + 8;    // histpick (shared across passes; self-reset)
    unsigned* dctrC  = ctrws + 16;   // cmp_countscan
    unsigned* dctrE  = ctrws + 24;   // ecompact_countscan
    unsigned* prefix = (unsigned*)alloc(64);
    int* rem0        = (int*)alloc(64);
    int* rem1        = (int*)alloc(64);
    int* tiesN       = (int*)alloc(64);
    int* ecnt1       = (int*)alloc(64);
    int* ecnt2       = (int*)alloc(64);
    int* ecnt3       = (int*)alloc(64);

    const int EB = (E0 + 255) / 256;

    auto build_csr = [&](const int* esrc, const int* edst, const float* eww, int n,
                         int* rowptr, int2* csrP,
                         const int* EinPtr, int EinImm, int gridE) {
        int nb = (n + 1023) / 1024;
        k_sum_scan<<<nb, 256, 0, stream>>>(cnt, bsum, n, rowptr + n, dctrS);
        k_chunk_scan<<<nb, 256, 0, stream>>>(cnt, bsum, rowptr, cursor, n);
        k_csr_fill<<<gridE, 256, 0, stream>>>(esrc, edst, eww, cursor, csrP, EinPtr, EinImm);
    };

    auto run_gcn = [&](const float* hin, const int* rowptr, const int2* csrP,
                       const float* W, const float* bias, float fill, int n, int lrelu,
                       float* outbuf, const float* bn_g, const float* bn_b,
                       const float* up_h, const int* up_pos) {
        k_gemm128<<<(n + GT_ROWS - 1) / GT_ROWS, 256, 0, stream>>>(hin, W, hWb, n, bn_g, bn_b, up_h, up_pos);
        k_deg_dinv<<<(n + 255) / 256, 256, 0, stream>>>(rowptr, csrP, fill, deg, dinv, n);
        k_gcn_gather<<<(n + 3) / 4, 256, 0, stream>>>(rowptr, csrP, deg, dinv, hWb,
                                                      bias, fill, n, lrelu, outbuf);
    };

    auto run_pool = [&](const float* xin, int n, int k, const float* pvec,
                        const float* g, const float* b,
                        const int* esrc_in, const int* edst_in, const float* ew_in,
                        const int* EinPtr, int EinImm,
                        int* pos, int* perm,
                        int* esrc_out, int* edst_out, float* ew_out, int* ecntOut) {
        int nb = (n + 1023) / 1024;
        k_score<<<(n + 3) / 4, 256, 0, stream>>>(xin, pvec, score, n, selws);
        k_histpick<<<64, 256, 0, stream>>>(score, n, 0, prefix, hist0, k, (const int*)nullptr, rem0, dctrH);
        k_histpick<<<64, 256, 0, stream>>>(score, n, 1, prefix, hist1, 0, rem0, rem1, dctrH);
        k_histpick<<<64, 256, 0, stream>>>(score, n, 2, prefix, hist2, 0, rem1, tiesN, dctrH);
        k_cmp_countscan<<<nb, 256, 0, stream>>>(score, n, prefix, bgt, beq, dctrC);
        k_cmp_assign<<<nb, 256, 0, stream>>>(score, n, k, prefix, tiesN, bgt, beq, pos, perm, vals);
        k_pool_bn<<<((size_t)k * HD + 255) / 256, 256, 0, stream>>>(xin, perm, vals, g, b, hbuf, k);
        k_ecompact_countscan<<<NBE, 256, 0, stream>>>(esrc_in, edst_in, ew_in, pos, EinPtr, EinImm, k,
                                                      bsumE, ecntOut, cnt, dctrE);
        k_ecompact_assign<<<NBE, 256, 0, stream>>>(esrc_in, edst_in, ew_in, pos, EinPtr, EinImm,
                                                   bsumE, esrc_out, edst_out, ew_out, cnt);
    };

    // ---- init counters (ws is re-poisoned before every launch) ----
    hipMemsetAsync((void*)ctrws, 0, 64 * 4, stream);
    hipMemsetAsync(cnt, 0, (size_t)N0 * 4, stream);

    // ---- edge weights + fused level-0 degree count ----
    k_edge_ew<<<EB, 256, 0, stream>>>(eattr, We_w, We_b, ew0, partials, E0);
    k_reduce_mm<<<1, 1024, 0, stream>>>(partials, EB, mmv);
    k_ew_norm_count<<<EB, 256, 0, stream>>>(ew0, mmv, dst0, cnt, E0);

    // ---- CSR level 0 ----
    build_csr(src0, dst0, ew0, N0, rowptr0, csrP0, (const int*)nullptr, E0, EB);

    // ---- level 0 (BN fused into GEMM A-staging) ----
    run_gcn(x, rowptr0, csrP0, Wdown, bdown, 1.0f, N0, 1, xs0, gnorm, bnorm, nullptr, nullptr);

    // ---- down: pool 1 / gcn 1 ----
    run_pool(xs0, N0, KP1, Wpool, gnorm + HD, bnorm + HD, src0, dst0, ew0,
             (const int*)nullptr, E0, pos1, perm1, src1, dst1, ew1, ecnt1);
    build_csr(src1, dst1, ew1, KP1, rowptr1, csrP1, ecnt1, 0, (E1C + 255) / 256);
    run_gcn(hbuf, rowptr1, csrP1, Wdown + 1 * HD * HD, bdown + 1 * HD, 1.0f, KP1, 1, xs1,
            nullptr, nullptr, nullptr, nullptr);

    // ---- down: pool 2 / gcn 2 ----
    run_pool(xs1, KP1, KP2, Wpool + HD, gnorm + 2 * HD, bnorm + 2 * HD, src1, dst1, ew1,
             ecnt1, 0, pos2, perm2, src2, dst2, ew2, ecnt2);
    build_csr(src2, dst2, ew2, KP2, rowptr2, csrP2, ecnt2, 0, (E2C + 255) / 256);
    run_gcn(hbuf, rowptr2, csrP2, Wdown + 2 * HD * HD, bdown + 2 * HD, 1.0f, KP2, 1, xs2,
            nullptr, nullptr, nullptr, nullptr);

    // ---- down: pool 3 / gcn 3 (no lrelu) ----
    run_pool(xs2, KP2, KP3, Wpool + 2 * HD, gnorm + 3 * HD, bnorm + 3 * HD, src2, dst2, ew2,
             ecnt2, 0, pos3, perm3, src3, dst3, ew3, ecnt3);
    build_csr(src3, dst3, ew3, KP3, rowptr3, csrP3, ecnt3, 0, (E3C + 255) / 256);
    run_gcn(hbuf, rowptr3, csrP3, Wdown + 3 * HD * HD, bdown + 3 * HD, 1.0f, KP3, 0, tmp,
            nullptr, nullptr, nullptr, nullptr);

    // ---- up 0: level 12500, CSR 2, fill=2 (unpool fused into GEMM) ----
    run_gcn(xs2, rowptr2, csrP2, Wup, bup, 2.0f, KP2, 1, tmp, nullptr, nullptr, tmp, pos3);

    // ---- up 1: level 25000, CSR 1 ----
    run_gcn(xs1, rowptr1, csrP1, Wup + 1 * HD * HD, bup + 1 * HD, 2.0f, KP1, 1, tmp,
            nullptr, nullptr, tmp, pos2);

    // ---- up 2: level 50000, CSR 0 (no lrelu) ----
    run_gcn(xs0, rowptr0, csrP0, Wup + 2 * HD * HD, bup + 2 * HD, 2.0f, N0, 0, tmp,
            nullptr, nullptr, tmp, pos1);

    // ---- readout (two-phase colsum + fused final) ----
    k_colsum_part<<<CSB, 256, 0, stream>>>(tmp, cpart, N0);
    k_colsum_final<<<1, 1024, 0, stream>>>(cpart, CSB, Wr, br, gr, brn, out);
}